// Round 1
// baseline (2132.874 us; speedup 1.0000x reference)
//
#include <hip/hip_runtime.h>
#include <hip/hip_bf16.h>
#include <math.h>

#define T_SEQ 4096
#define BATCH 2
#define DM 256
#define DI 512
#define DS 16
#define ROWS (BATCH * T_SEQ)   // 8192

__device__ __forceinline__ float siluf(float x) { return x / (1.f + __expf(-x)); }
__device__ __forceinline__ float softplusf(float x) {
    return fmaxf(x, 0.f) + log1pf(__expf(-fabsf(x)));
}

// ---------------------------------------------------------------------------
// Generic fp32 tiled GEMM: C[M,N] (+)= Amap(A)[M,K] * B[K,N]
// BM=BN=64, BK=16, 256 threads, 4x4 per thread.
// flipA: row r of A is read at (r ^ 4095) -- time-flip within batch (T=4096).
// accum: C += instead of C =.
// ---------------------------------------------------------------------------
#define BM 64
#define BN 64
#define BKK 16

__global__ __launch_bounds__(256)
void gemm64(const float* __restrict__ A, const float* __restrict__ B,
            float* __restrict__ C, int N, int K,
            int lda, int ldb, int ldc, int flipA, int accum)
{
    __shared__ float As[BKK][BM + 4];
    __shared__ float Bs[BKK][BN + 4];
    const int tid = threadIdx.x;
    const int gx = blockIdx.x, gy = blockIdx.y;
    const int row0 = gy * BM, col0 = gx * BN;
    const int ty = tid >> 4, tx = tid & 15;

    const int arow_l = tid >> 2;           // 0..63
    const int acol_l = (tid & 3) * 4;      // 0,4,8,12
    const int brow_l = tid >> 4;           // 0..15
    const int bcol_l = (tid & 15) * 4;     // 0..60

    int arow_g = row0 + arow_l;
    if (flipA) arow_g ^= (T_SEQ - 1);
    const float* Aptr = A + (size_t)arow_g * lda + acol_l;

    float acc[4][4] = {};

    for (int k0 = 0; k0 < K; k0 += BKK) {
        float4 av = *reinterpret_cast<const float4*>(Aptr + k0);
        As[acol_l + 0][arow_l] = av.x;
        As[acol_l + 1][arow_l] = av.y;
        As[acol_l + 2][arow_l] = av.z;
        As[acol_l + 3][arow_l] = av.w;

        int bn = col0 + bcol_l;
        const float* Bp = B + (size_t)(k0 + brow_l) * ldb + bn;
        float4 bv;
        if (bn + 3 < N) {
            bv = *reinterpret_cast<const float4*>(Bp);
        } else {
            bv.x = (bn + 0 < N) ? Bp[0] : 0.f;
            bv.y = (bn + 1 < N) ? Bp[1] : 0.f;
            bv.z = (bn + 2 < N) ? Bp[2] : 0.f;
            bv.w = (bn + 3 < N) ? Bp[3] : 0.f;
        }
        *reinterpret_cast<float4*>(&Bs[brow_l][bcol_l]) = bv;

        __syncthreads();
        #pragma unroll
        for (int k = 0; k < BKK; ++k) {
            float4 a4 = *reinterpret_cast<const float4*>(&As[k][ty * 4]);
            float4 b4 = *reinterpret_cast<const float4*>(&Bs[k][tx * 4]);
            float avv[4] = {a4.x, a4.y, a4.z, a4.w};
            float bvv[4] = {b4.x, b4.y, b4.z, b4.w};
            #pragma unroll
            for (int i = 0; i < 4; ++i)
                #pragma unroll
                for (int j = 0; j < 4; ++j)
                    acc[i][j] = fmaf(avv[i], bvv[j], acc[i][j]);
        }
        __syncthreads();
    }

    #pragma unroll
    for (int i = 0; i < 4; ++i) {
        int r = row0 + ty * 4 + i;
        #pragma unroll
        for (int j = 0; j < 4; ++j) {
            int c = col0 + tx * 4 + j;
            if (c < N) {
                size_t o = (size_t)r * ldc + c;
                C[o] = accum ? (C[o] + acc[i][j]) : acc[i][j];
            }
        }
    }
}

// ---------------------------------------------------------------------------
// Fuse W_out (512x256) @ merge_W[mrow0:mrow0+256, :] (256x256) -> Wf (512x256)
// ---------------------------------------------------------------------------
__global__ __launch_bounds__(256)
void fusew_kernel(const float* __restrict__ W_out, const float* __restrict__ merge,
                  float* __restrict__ Wfused, int mrow0)
{
    int idx = blockIdx.x * 256 + threadIdx.x;   // d*256 + j
    int d = idx >> 8, j = idx & 255;
    float acc = 0.f;
    const float* wr = W_out + d * 256;
    const float* mc = merge + (size_t)mrow0 * 256 + j;
    #pragma unroll 4
    for (int m = 0; m < 256; ++m)
        acc = fmaf(wr[m], mc[(size_t)m * 256], acc);
    Wfused[idx] = acc;
}

// ---------------------------------------------------------------------------
// Causal depthwise conv (4 taps) + bias + silu.  Reads first 512 cols of xz.
// ---------------------------------------------------------------------------
__global__ __launch_bounds__(256)
void conv_kernel(const float* __restrict__ xz, const float* __restrict__ w,
                 const float* __restrict__ bias, float* __restrict__ xi)
{
    int idx = blockIdx.x * 256 + threadIdx.x;   // r*512 + d
    int r = idx >> 9, d = idx & 511;
    int t = r & (T_SEQ - 1);
    float acc = bias[d];
    #pragma unroll
    for (int k = 0; k < 4; ++k) {
        int tt = t + k - 3;
        if (tt >= 0)
            acc = fmaf(w[d * 4 + k], xz[(size_t)(r + k - 3) * 1024 + d], acc);
    }
    xi[idx] = siluf(acc);
}

// ---------------------------------------------------------------------------
// dt = softplus(xdbl[:, :16] @ W_dt + b_dt)
// ---------------------------------------------------------------------------
__global__ __launch_bounds__(256)
void dt_kernel(const float* __restrict__ xdbl, const float* __restrict__ W_dt,
               const float* __restrict__ b_dt, float* __restrict__ dt)
{
    int idx = blockIdx.x * 256 + threadIdx.x;   // r*512 + n
    int r = idx >> 9, n = idx & 511;
    const float* xr = xdbl + (size_t)r * 48;
    float acc = b_dt[n];
    #pragma unroll
    for (int k = 0; k < 16; ++k)
        acc = fmaf(xr[k], W_dt[k * 512 + n], acc);
    dt[idx] = softplusf(acc);
}

// ---------------------------------------------------------------------------
// Selective-scan.  One wave = 4 channels x 16 states.  512 waves total.
// lane = c*16 + n ; h = exp(dt*A)*h + dt*B*xi ; y = sum_n h*C
// ---------------------------------------------------------------------------
__global__ __launch_bounds__(256)
void scan_kernel(const float* __restrict__ dt_f, const float* __restrict__ dt_b,
                 const float* __restrict__ xi_f, const float* __restrict__ xi_b,
                 const float* __restrict__ xd_f, const float* __restrict__ xd_b,
                 const float* __restrict__ Al_f, const float* __restrict__ Al_b,
                 float* __restrict__ y_f, float* __restrict__ y_b)
{
    int wid = (blockIdx.x * 256 + threadIdx.x) >> 6;
    int lane = threadIdx.x & 63;
    int dir = wid >> 8;
    int rem = wid & 255;
    int b = rem >> 7;
    int d0 = (rem & 127) << 2;
    int c = lane >> 4, n = lane & 15;
    int d = d0 + c;

    const float* dt = dir ? dt_b : dt_f;
    const float* xi = dir ? xi_b : xi_f;
    const float* xd = dir ? xd_b : xd_f;
    const float* Al = dir ? Al_b : Al_f;
    float*       y  = dir ? y_b  : y_f;

    const float a = -expf(Al[d * 16 + n]);
    size_t base = (size_t)b * T_SEQ;
    const float* dtp = dt + base * 512 + d;
    const float* xip = xi + base * 512 + d;
    const float* xdp = xd + base * 48;
    float*       yp  = y  + base * 512 + d;

    float h = 0.f;
    for (int t = 0; t < T_SEQ; ++t) {
        float dtv = *dtp;
        float xiv = *xip;
        float bm  = xdp[16 + n];
        float cm  = xdp[32 + n];
        float dA  = __expf(dtv * a);
        h = fmaf(dA, h, dtv * bm * xiv);
        float contrib = h * cm;
        contrib += __shfl_xor(contrib, 8, 16);
        contrib += __shfl_xor(contrib, 4, 16);
        contrib += __shfl_xor(contrib, 2, 16);
        contrib += __shfl_xor(contrib, 1, 16);
        if (n == 0) *yp = contrib;
        dtp += 512; xip += 512; xdp += 48; yp += 512;
    }
}

// ---------------------------------------------------------------------------
// Gate: y = (y_scan + xi*D) * silu(z)   (in-place on y)
// ---------------------------------------------------------------------------
__global__ __launch_bounds__(256)
void gate_kernel(const float* __restrict__ xz, const float* __restrict__ xi,
                 const float* __restrict__ Dv, float* __restrict__ y)
{
    int idx = blockIdx.x * 256 + threadIdx.x;   // r*512 + d
    int r = idx >> 9, d = idx & 511;
    float z = xz[(size_t)r * 1024 + 512 + d];
    y[idx] = fmaf(xi[idx], Dv[d], y[idx]) * siluf(z);
}

// ---------------------------------------------------------------------------
extern "C" void kernel_launch(void* const* d_in, const int* in_sizes, int n_in,
                              void* d_out, int out_size, void* d_ws, size_t ws_size,
                              hipStream_t stream)
{
    const float* x       = (const float*)d_in[0];
    const float* fW_in   = (const float*)d_in[1];
    const float* fconv_w = (const float*)d_in[2];
    const float* fconv_b = (const float*)d_in[3];
    const float* fW_x    = (const float*)d_in[4];
    const float* fW_dt   = (const float*)d_in[5];
    const float* fb_dt   = (const float*)d_in[6];
    const float* fA_log  = (const float*)d_in[7];
    const float* fD      = (const float*)d_in[8];
    const float* fW_out  = (const float*)d_in[9];
    const float* bW_in   = (const float*)d_in[10];
    const float* bconv_w = (const float*)d_in[11];
    const float* bconv_b = (const float*)d_in[12];
    const float* bW_x    = (const float*)d_in[13];
    const float* bW_dt   = (const float*)d_in[14];
    const float* bb_dt   = (const float*)d_in[15];
    const float* bA_log  = (const float*)d_in[16];
    const float* bD      = (const float*)d_in[17];
    const float* bW_out  = (const float*)d_in[18];
    const float* merge   = (const float*)d_in[19];
    float* out = (float*)d_out;

    char* ws = (char*)d_ws;
    float* xz_f = (float*)ws; ws += (size_t)ROWS * 1024 * 4;
    float* xz_b = (float*)ws; ws += (size_t)ROWS * 1024 * 4;
    float* xi_f = (float*)ws; ws += (size_t)ROWS * 512 * 4;
    float* xi_b = (float*)ws; ws += (size_t)ROWS * 512 * 4;
    float* xd_f = (float*)ws; ws += (size_t)ROWS * 48 * 4;
    float* xd_b = (float*)ws; ws += (size_t)ROWS * 48 * 4;
    float* dt_f = (float*)ws; ws += (size_t)ROWS * 512 * 4;
    float* dt_b = (float*)ws; ws += (size_t)ROWS * 512 * 4;
    float* y_f  = (float*)ws; ws += (size_t)ROWS * 512 * 4;
    float* y_b  = (float*)ws; ws += (size_t)ROWS * 512 * 4;
    float* Wf   = (float*)ws; ws += (size_t)512 * 256 * 4;
    float* Wb   = (float*)ws; ws += (size_t)512 * 256 * 4;

    dim3 blk(256);

    // G0: fused output weights
    fusew_kernel<<<512, blk, 0, stream>>>(fW_out, merge, Wf, 0);
    fusew_kernel<<<512, blk, 0, stream>>>(bW_out, merge, Wb, 256);

    // G1: xz = x @ W_in (bw reads time-flipped x)
    dim3 g1(1024 / BN, ROWS / BM);
    gemm64<<<g1, blk, 0, stream>>>(x, fW_in, xz_f, 1024, 256, 256, 1024, 1024, 0, 0);
    gemm64<<<g1, blk, 0, stream>>>(x, bW_in, xz_b, 1024, 256, 256, 1024, 1024, 1, 0);

    // conv + silu
    int pw_blocks = ROWS * 512 / 256;
    conv_kernel<<<pw_blocks, blk, 0, stream>>>(xz_f, fconv_w, fconv_b, xi_f);
    conv_kernel<<<pw_blocks, blk, 0, stream>>>(xz_b, bconv_w, bconv_b, xi_b);

    // G2: xdbl = xi @ W_x  (N=48)
    dim3 g2(1, ROWS / BM);
    gemm64<<<g2, blk, 0, stream>>>(xi_f, fW_x, xd_f, 48, 512, 512, 48, 48, 0, 0);
    gemm64<<<g2, blk, 0, stream>>>(xi_b, bW_x, xd_b, 48, 512, 512, 48, 48, 0, 0);

    // G3: dt
    dt_kernel<<<pw_blocks, blk, 0, stream>>>(xd_f, fW_dt, fb_dt, dt_f);
    dt_kernel<<<pw_blocks, blk, 0, stream>>>(xd_b, bW_dt, bb_dt, dt_b);

    // scan (both directions in one launch)
    scan_kernel<<<128, blk, 0, stream>>>(dt_f, dt_b, xi_f, xi_b, xd_f, xd_b,
                                         fA_log, bA_log, y_f, y_b);

    // gate
    gate_kernel<<<pw_blocks, blk, 0, stream>>>(xz_f, xi_f, fD, y_f);
    gate_kernel<<<pw_blocks, blk, 0, stream>>>(xz_b, xi_b, bD, y_b);

    // G5: out = ygate_f @ Wf + flip(ygate_b) @ Wb
    dim3 g5(256 / BN, ROWS / BM);
    gemm64<<<g5, blk, 0, stream>>>(y_f, Wf, out, 256, 512, 512, 256, 256, 0, 0);
    gemm64<<<g5, blk, 0, stream>>>(y_b, Wb, out, 256, 512, 512, 256, 256, 1, 1);
}

// Round 2
// 609.406 us; speedup vs baseline: 3.4999x; 3.4999x over previous
//
#include <hip/hip_runtime.h>
#include <hip/hip_bf16.h>
#include <math.h>

#define T_SEQ 4096
#define BATCH 2
#define DM 256
#define DI 512
#define DS 16
#define ROWS (BATCH * T_SEQ)   // 8192
#define NCHUNK 64
#define CLEN   64              // T_SEQ / NCHUNK

__device__ __forceinline__ float siluf(float x) { return x / (1.f + __expf(-x)); }
__device__ __forceinline__ float softplusf(float x) {
    return fmaxf(x, 0.f) + log1pf(__expf(-fabsf(x)));
}

// ---------------------------------------------------------------------------
// Generic fp32 tiled GEMM: C[M,N] (+)= Amap(A)[M,K] * B[K,N]
// BM=BN=64, BK=16, 256 threads, 4x4 per thread.
// flipA: row r of A is read at (r ^ 4095) -- time-flip within batch (T=4096).
// accum: C += instead of C =.
// ---------------------------------------------------------------------------
#define BM 64
#define BN 64
#define BKK 16

__global__ __launch_bounds__(256)
void gemm64(const float* __restrict__ A, const float* __restrict__ B,
            float* __restrict__ C, int N, int K,
            int lda, int ldb, int ldc, int flipA, int accum)
{
    __shared__ float As[BKK][BM + 4];
    __shared__ float Bs[BKK][BN + 4];
    const int tid = threadIdx.x;
    const int gx = blockIdx.x, gy = blockIdx.y;
    const int row0 = gy * BM, col0 = gx * BN;
    const int ty = tid >> 4, tx = tid & 15;

    const int arow_l = tid >> 2;           // 0..63
    const int acol_l = (tid & 3) * 4;      // 0,4,8,12
    const int brow_l = tid >> 4;           // 0..15
    const int bcol_l = (tid & 15) * 4;     // 0..60

    int arow_g = row0 + arow_l;
    if (flipA) arow_g ^= (T_SEQ - 1);
    const float* Aptr = A + (size_t)arow_g * lda + acol_l;

    float acc[4][4] = {};

    for (int k0 = 0; k0 < K; k0 += BKK) {
        float4 av = *reinterpret_cast<const float4*>(Aptr + k0);
        As[acol_l + 0][arow_l] = av.x;
        As[acol_l + 1][arow_l] = av.y;
        As[acol_l + 2][arow_l] = av.z;
        As[acol_l + 3][arow_l] = av.w;

        int bn = col0 + bcol_l;
        const float* Bp = B + (size_t)(k0 + brow_l) * ldb + bn;
        float4 bv;
        if (bn + 3 < N) {
            bv = *reinterpret_cast<const float4*>(Bp);
        } else {
            bv.x = (bn + 0 < N) ? Bp[0] : 0.f;
            bv.y = (bn + 1 < N) ? Bp[1] : 0.f;
            bv.z = (bn + 2 < N) ? Bp[2] : 0.f;
            bv.w = (bn + 3 < N) ? Bp[3] : 0.f;
        }
        *reinterpret_cast<float4*>(&Bs[brow_l][bcol_l]) = bv;

        __syncthreads();
        #pragma unroll
        for (int k = 0; k < BKK; ++k) {
            float4 a4 = *reinterpret_cast<const float4*>(&As[k][ty * 4]);
            float4 b4 = *reinterpret_cast<const float4*>(&Bs[k][tx * 4]);
            float avv[4] = {a4.x, a4.y, a4.z, a4.w};
            float bvv[4] = {b4.x, b4.y, b4.z, b4.w};
            #pragma unroll
            for (int i = 0; i < 4; ++i)
                #pragma unroll
                for (int j = 0; j < 4; ++j)
                    acc[i][j] = fmaf(avv[i], bvv[j], acc[i][j]);
        }
        __syncthreads();
    }

    #pragma unroll
    for (int i = 0; i < 4; ++i) {
        int r = row0 + ty * 4 + i;
        #pragma unroll
        for (int j = 0; j < 4; ++j) {
            int c = col0 + tx * 4 + j;
            if (c < N) {
                size_t o = (size_t)r * ldc + c;
                C[o] = accum ? (C[o] + acc[i][j]) : acc[i][j];
            }
        }
    }
}

// ---------------------------------------------------------------------------
// Fuse W_out (512x256) @ merge_W[mrow0:mrow0+256, :] (256x256) -> Wf (512x256)
// ---------------------------------------------------------------------------
__global__ __launch_bounds__(256)
void fusew_kernel(const float* __restrict__ W_out, const float* __restrict__ merge,
                  float* __restrict__ Wfused, int mrow0)
{
    int idx = blockIdx.x * 256 + threadIdx.x;   // d*256 + j
    int d = idx >> 8, j = idx & 255;
    float acc = 0.f;
    const float* wr = W_out + d * 256;
    const float* mc = merge + (size_t)mrow0 * 256 + j;
    #pragma unroll 4
    for (int m = 0; m < 256; ++m)
        acc = fmaf(wr[m], mc[(size_t)m * 256], acc);
    Wfused[idx] = acc;
}

// ---------------------------------------------------------------------------
// Causal depthwise conv (4 taps) + bias + silu.  Reads first 512 cols of xz.
// ---------------------------------------------------------------------------
__global__ __launch_bounds__(256)
void conv_kernel(const float* __restrict__ xz, const float* __restrict__ w,
                 const float* __restrict__ bias, float* __restrict__ xi)
{
    int idx = blockIdx.x * 256 + threadIdx.x;   // r*512 + d
    int r = idx >> 9, d = idx & 511;
    int t = r & (T_SEQ - 1);
    float acc = bias[d];
    #pragma unroll
    for (int k = 0; k < 4; ++k) {
        int tt = t + k - 3;
        if (tt >= 0)
            acc = fmaf(w[d * 4 + k], xz[(size_t)(r + k - 3) * 1024 + d], acc);
    }
    xi[idx] = siluf(acc);
}

// ---------------------------------------------------------------------------
// dt = softplus(xdbl[:, :16] @ W_dt + b_dt)
// ---------------------------------------------------------------------------
__global__ __launch_bounds__(256)
void dt_kernel(const float* __restrict__ xdbl, const float* __restrict__ W_dt,
               const float* __restrict__ b_dt, float* __restrict__ dt)
{
    int idx = blockIdx.x * 256 + threadIdx.x;   // r*512 + n
    int r = idx >> 9, n = idx & 511;
    const float* xr = xdbl + (size_t)r * 48;
    float acc = b_dt[n];
    #pragma unroll
    for (int k = 0; k < 16; ++k)
        acc = fmaf(xr[k], W_dt[k * 512 + n], acc);
    dt[idx] = softplusf(acc);
}

// ---------------------------------------------------------------------------
// Chunked parallel scan.  Wave layout: lane = c*16 + n, 4 channels/wave.
// wid = ((dir*2+b)*NCHUNK + chunk)*128 + dgrp
// Summary index: (((dir*2+b)*NCHUNK + chunk)*512 + d)*16 + n
// ---------------------------------------------------------------------------
__device__ __forceinline__ void scan_decode(int wid, int lane,
    int& dir, int& b, int& chunk, int& d, int& n)
{
    int dgrp = wid & 127;
    int tmp = wid >> 7;
    chunk = tmp & (NCHUNK - 1);
    int db = tmp >> 6;
    b = db & 1; dir = db >> 1;
    int c = lane >> 4; n = lane & 15;
    d = dgrp * 4 + c;
}

// pass1: per-chunk local scan with h_in = 0; emit prod(dA) and local h.
__global__ __launch_bounds__(256)
void scan_pass1(const float* __restrict__ dt_f, const float* __restrict__ dt_b,
                const float* __restrict__ xi_f, const float* __restrict__ xi_b,
                const float* __restrict__ xd_f, const float* __restrict__ xd_b,
                const float* __restrict__ Al_f, const float* __restrict__ Al_b,
                float* __restrict__ Acum, float* __restrict__ Hloc)
{
    int wid = blockIdx.x * 4 + (threadIdx.x >> 6);
    int lane = threadIdx.x & 63;
    int dir, b, chunk, d, n;
    scan_decode(wid, lane, dir, b, chunk, d, n);

    const float* dt = dir ? dt_b : dt_f;
    const float* xi = dir ? xi_b : xi_f;
    const float* xd = dir ? xd_b : xd_f;
    const float* Al = dir ? Al_b : Al_f;

    const float a = -expf(Al[d * 16 + n]);
    size_t row0 = (size_t)b * T_SEQ + (size_t)chunk * CLEN;
    const float* dtp = dt + row0 * 512 + d;
    const float* xip = xi + row0 * 512 + d;
    const float* xdp = xd + row0 * 48;

    float h = 0.f, ac = 1.f;
    #pragma unroll 4
    for (int t = 0; t < CLEN; ++t) {
        float dtv = *dtp;
        float xiv = *xip;
        float bm  = xdp[16 + n];
        float dA  = __expf(dtv * a);
        h = fmaf(dA, h, dtv * bm * xiv);
        ac *= dA;
        dtp += 512; xip += 512; xdp += 48;
    }
    size_t si = ((size_t)(((dir * 2 + b) * NCHUNK + chunk) * 512 + d)) * 16 + n;
    Acum[si] = ac;
    Hloc[si] = h;
}

// pass2: sequential scan over chunk summaries -> h_in per chunk.
__global__ __launch_bounds__(256)
void scan_pass2(const float* __restrict__ Acum, const float* __restrict__ Hloc,
                float* __restrict__ Hin)
{
    int tid = blockIdx.x * 256 + threadIdx.x;   // ((dir*2+b)*512 + d)*16 + n
    int db = tid >> 13;                          // dir*2+b
    int dn = tid & 8191;                         // d*16+n
    size_t base = (size_t)db * NCHUNK * 8192 + dn;
    float h = 0.f;
    #pragma unroll 8
    for (int c = 0; c < NCHUNK; ++c) {
        size_t si = base + (size_t)c * 8192;
        Hin[si] = h;
        h = fmaf(Acum[si], h, Hloc[si]);
    }
}

// pass3: replay each chunk from correct h_in, emit y.
__global__ __launch_bounds__(256)
void scan_pass3(const float* __restrict__ dt_f, const float* __restrict__ dt_b,
                const float* __restrict__ xi_f, const float* __restrict__ xi_b,
                const float* __restrict__ xd_f, const float* __restrict__ xd_b,
                const float* __restrict__ Al_f, const float* __restrict__ Al_b,
                const float* __restrict__ Hin,
                float* __restrict__ y_f, float* __restrict__ y_b)
{
    int wid = blockIdx.x * 4 + (threadIdx.x >> 6);
    int lane = threadIdx.x & 63;
    int dir, b, chunk, d, n;
    scan_decode(wid, lane, dir, b, chunk, d, n);

    const float* dt = dir ? dt_b : dt_f;
    const float* xi = dir ? xi_b : xi_f;
    const float* xd = dir ? xd_b : xd_f;
    const float* Al = dir ? Al_b : Al_f;
    float*       y  = dir ? y_b  : y_f;

    const float a = -expf(Al[d * 16 + n]);
    size_t row0 = (size_t)b * T_SEQ + (size_t)chunk * CLEN;
    const float* dtp = dt + row0 * 512 + d;
    const float* xip = xi + row0 * 512 + d;
    const float* xdp = xd + row0 * 48;
    float*       yp  = y  + row0 * 512 + d;

    size_t si = ((size_t)(((dir * 2 + b) * NCHUNK + chunk) * 512 + d)) * 16 + n;
    float h = Hin[si];

    for (int t = 0; t < CLEN; ++t) {
        float dtv = *dtp;
        float xiv = *xip;
        float bm  = xdp[16 + n];
        float cm  = xdp[32 + n];
        float dA  = __expf(dtv * a);
        h = fmaf(dA, h, dtv * bm * xiv);
        float contrib = h * cm;
        contrib += __shfl_xor(contrib, 8, 16);
        contrib += __shfl_xor(contrib, 4, 16);
        contrib += __shfl_xor(contrib, 2, 16);
        contrib += __shfl_xor(contrib, 1, 16);
        if (n == 0) *yp = contrib;
        dtp += 512; xip += 512; xdp += 48; yp += 512;
    }
}

// ---------------------------------------------------------------------------
// Gate: y = (y_scan + xi*D) * silu(z)   (in-place on y)
// ---------------------------------------------------------------------------
__global__ __launch_bounds__(256)
void gate_kernel(const float* __restrict__ xz, const float* __restrict__ xi,
                 const float* __restrict__ Dv, float* __restrict__ y)
{
    int idx = blockIdx.x * 256 + threadIdx.x;   // r*512 + d
    int r = idx >> 9, d = idx & 511;
    float z = xz[(size_t)r * 1024 + 512 + d];
    y[idx] = fmaf(xi[idx], Dv[d], y[idx]) * siluf(z);
}

// ---------------------------------------------------------------------------
extern "C" void kernel_launch(void* const* d_in, const int* in_sizes, int n_in,
                              void* d_out, int out_size, void* d_ws, size_t ws_size,
                              hipStream_t stream)
{
    const float* x       = (const float*)d_in[0];
    const float* fW_in   = (const float*)d_in[1];
    const float* fconv_w = (const float*)d_in[2];
    const float* fconv_b = (const float*)d_in[3];
    const float* fW_x    = (const float*)d_in[4];
    const float* fW_dt   = (const float*)d_in[5];
    const float* fb_dt   = (const float*)d_in[6];
    const float* fA_log  = (const float*)d_in[7];
    const float* fD      = (const float*)d_in[8];
    const float* fW_out  = (const float*)d_in[9];
    const float* bW_in   = (const float*)d_in[10];
    const float* bconv_w = (const float*)d_in[11];
    const float* bconv_b = (const float*)d_in[12];
    const float* bW_x    = (const float*)d_in[13];
    const float* bW_dt   = (const float*)d_in[14];
    const float* bb_dt   = (const float*)d_in[15];
    const float* bA_log  = (const float*)d_in[16];
    const float* bD      = (const float*)d_in[17];
    const float* bW_out  = (const float*)d_in[18];
    const float* merge   = (const float*)d_in[19];
    float* out = (float*)d_out;

    char* ws = (char*)d_ws;
    float* xz_f = (float*)ws; ws += (size_t)ROWS * 1024 * 4;
    float* xz_b = (float*)ws; ws += (size_t)ROWS * 1024 * 4;
    float* xi_f = (float*)ws; ws += (size_t)ROWS * 512 * 4;
    float* xi_b = (float*)ws; ws += (size_t)ROWS * 512 * 4;
    float* xd_f = (float*)ws; ws += (size_t)ROWS * 48 * 4;
    float* xd_b = (float*)ws; ws += (size_t)ROWS * 48 * 4;
    float* dt_f = (float*)ws; ws += (size_t)ROWS * 512 * 4;
    float* dt_b = (float*)ws; ws += (size_t)ROWS * 512 * 4;
    float* y_f  = (float*)ws; ws += (size_t)ROWS * 512 * 4;
    float* y_b  = (float*)ws; ws += (size_t)ROWS * 512 * 4;
    float* Wf   = (float*)ws; ws += (size_t)512 * 256 * 4;
    float* Wb   = (float*)ws; ws += (size_t)512 * 256 * 4;
    float* Acum = (float*)ws; ws += (size_t)4 * NCHUNK * 8192 * 4;
    float* Hloc = (float*)ws; ws += (size_t)4 * NCHUNK * 8192 * 4;
    float* Hin  = (float*)ws; ws += (size_t)4 * NCHUNK * 8192 * 4;

    dim3 blk(256);

    // G0: fused output weights
    fusew_kernel<<<512, blk, 0, stream>>>(fW_out, merge, Wf, 0);
    fusew_kernel<<<512, blk, 0, stream>>>(bW_out, merge, Wb, 256);

    // G1: xz = x @ W_in (bw reads time-flipped x)
    dim3 g1(1024 / BN, ROWS / BM);
    gemm64<<<g1, blk, 0, stream>>>(x, fW_in, xz_f, 1024, 256, 256, 1024, 1024, 0, 0);
    gemm64<<<g1, blk, 0, stream>>>(x, bW_in, xz_b, 1024, 256, 256, 1024, 1024, 1, 0);

    // conv + silu
    int pw_blocks = ROWS * 512 / 256;
    conv_kernel<<<pw_blocks, blk, 0, stream>>>(xz_f, fconv_w, fconv_b, xi_f);
    conv_kernel<<<pw_blocks, blk, 0, stream>>>(xz_b, bconv_w, bconv_b, xi_b);

    // G2: xdbl = xi @ W_x  (N=48)
    dim3 g2(1, ROWS / BM);
    gemm64<<<g2, blk, 0, stream>>>(xi_f, fW_x, xd_f, 48, 512, 512, 48, 48, 0, 0);
    gemm64<<<g2, blk, 0, stream>>>(xi_b, bW_x, xd_b, 48, 512, 512, 48, 48, 0, 0);

    // G3: dt
    dt_kernel<<<pw_blocks, blk, 0, stream>>>(xd_f, fW_dt, fb_dt, dt_f);
    dt_kernel<<<pw_blocks, blk, 0, stream>>>(xd_b, bW_dt, bb_dt, dt_b);

    // chunked parallel scan: 32768 waves in pass1/pass3
    scan_pass1<<<8192, blk, 0, stream>>>(dt_f, dt_b, xi_f, xi_b, xd_f, xd_b,
                                         fA_log, bA_log, Acum, Hloc);
    scan_pass2<<<128, blk, 0, stream>>>(Acum, Hloc, Hin);
    scan_pass3<<<8192, blk, 0, stream>>>(dt_f, dt_b, xi_f, xi_b, xd_f, xd_b,
                                         fA_log, bA_log, Hin, y_f, y_b);

    // gate
    gate_kernel<<<pw_blocks, blk, 0, stream>>>(xz_f, xi_f, fD, y_f);
    gate_kernel<<<pw_blocks, blk, 0, stream>>>(xz_b, xi_b, bD, y_b);

    // G5: out = ygate_f @ Wf + flip(ygate_b) @ Wb
    dim3 g5(256 / BN, ROWS / BM);
    gemm64<<<g5, blk, 0, stream>>>(y_f, Wf, out, 256, 512, 512, 256, 256, 0, 0);
    gemm64<<<g5, blk, 0, stream>>>(y_b, Wb, out, 256, 512, 512, 256, 256, 1, 1);
}

// Round 3
// 460.497 us; speedup vs baseline: 4.6317x; 1.3234x over previous
//
#include <hip/hip_runtime.h>
#include <hip/hip_bf16.h>
#include <math.h>

#define T_SEQ 4096
#define BATCH 2
#define DM 256
#define DI 512
#define DS 16
#define ROWS (BATCH * T_SEQ)   // 8192
#define NCHUNK 64
#define CLEN   64              // T_SEQ / NCHUNK

__device__ __forceinline__ float siluf(float x) { return x / (1.f + __expf(-x)); }
__device__ __forceinline__ float softplusf(float x) {
    return fmaxf(x, 0.f) + log1pf(__expf(-fabsf(x)));
}

// ---------------------------------------------------------------------------
// Tiled fp32 GEMM, BM=128, BK=16, 256 threads, TM=8.  BNv in {128,64}, TN=BNv/16.
// flipA: row r of A read at (r ^ 4095).  accum: C += .
// Bs col-swizzle (pad 4 per 32) keeps ds_read conflicts at 2-way (free).
// ---------------------------------------------------------------------------
__device__ __forceinline__ int bswz(int c) { return c + ((c >> 5) << 2); }

template<int BNv, int TN>
__global__ __launch_bounds__(256)
void gemm128(const float* __restrict__ A, const float* __restrict__ B,
             float* __restrict__ C, int K,
             int lda, int ldb, int ldc, int flipA, int accum)
{
    __shared__ float As[16][128 + 4];
    __shared__ float Bs[16][BNv + (BNv >> 5) * 4];
    const int tid = threadIdx.x;
    const int row0 = blockIdx.y * 128, col0 = blockIdx.x * BNv;
    const int ty = tid >> 4, tx = tid & 15;

    const int arow_l = tid >> 1;          // 0..127
    const int acol_l = (tid & 1) * 8;     // 0 or 8
    int arow_g = row0 + arow_l;
    if (flipA) arow_g ^= (T_SEQ - 1);
    const float* Aptr = A + (size_t)arow_g * lda + acol_l;

    const int brow_l = tid >> 4;                    // 0..15
    const int bcol_l = (tid & 15) * (BNv / 16);     // stride TN
    const float* Bptr = B + (size_t)brow_l * ldb + col0 + bcol_l;

    float acc[8][TN] = {};

    for (int k0 = 0; k0 < K; k0 += 16) {
        float4 a0 = *reinterpret_cast<const float4*>(Aptr + k0);
        float4 a1 = *reinterpret_cast<const float4*>(Aptr + k0 + 4);
        As[acol_l + 0][arow_l] = a0.x;
        As[acol_l + 1][arow_l] = a0.y;
        As[acol_l + 2][arow_l] = a0.z;
        As[acol_l + 3][arow_l] = a0.w;
        As[acol_l + 4][arow_l] = a1.x;
        As[acol_l + 5][arow_l] = a1.y;
        As[acol_l + 6][arow_l] = a1.z;
        As[acol_l + 7][arow_l] = a1.w;

        const float* bp = Bptr + (size_t)k0 * ldb;
        if (TN == 8) {
            float4 b0 = *reinterpret_cast<const float4*>(bp);
            float4 b1 = *reinterpret_cast<const float4*>(bp + 4);
            *reinterpret_cast<float4*>(&Bs[brow_l][bswz(bcol_l)]) = b0;
            *reinterpret_cast<float4*>(&Bs[brow_l][bswz(bcol_l) + 4]) = b1;
        } else {
            float4 b0 = *reinterpret_cast<const float4*>(bp);
            *reinterpret_cast<float4*>(&Bs[brow_l][bswz(bcol_l)]) = b0;
        }

        __syncthreads();
        #pragma unroll
        for (int k = 0; k < 16; ++k) {
            float4 a4l = *reinterpret_cast<const float4*>(&As[k][ty * 8]);
            float4 a4h = *reinterpret_cast<const float4*>(&As[k][ty * 8 + 4]);
            float av[8] = {a4l.x, a4l.y, a4l.z, a4l.w, a4h.x, a4h.y, a4h.z, a4h.w};
            float bv[TN];
            {
                float4 b4l = *reinterpret_cast<const float4*>(&Bs[k][bswz(tx * TN)]);
                bv[0] = b4l.x; bv[1] = b4l.y; bv[2] = b4l.z; bv[3] = b4l.w;
                if (TN == 8) {
                    float4 b4h = *reinterpret_cast<const float4*>(&Bs[k][bswz(tx * TN) + 4]);
                    bv[4] = b4h.x; bv[5] = b4h.y; bv[6] = b4h.z; bv[7] = b4h.w;
                }
            }
            #pragma unroll
            for (int i = 0; i < 8; ++i)
                #pragma unroll
                for (int j = 0; j < TN; ++j)
                    acc[i][j] = fmaf(av[i], bv[j], acc[i][j]);
        }
        __syncthreads();
    }

    #pragma unroll
    for (int i = 0; i < 8; ++i) {
        int r = row0 + ty * 8 + i;
        float* cp = C + (size_t)r * ldc + col0 + tx * TN;
        #pragma unroll
        for (int j = 0; j < TN; j += 4) {
            float4 v = make_float4(acc[i][j], acc[i][j+1], acc[i][j+2], acc[i][j+3]);
            if (accum) {
                float4 o = *reinterpret_cast<float4*>(cp + j);
                v.x += o.x; v.y += o.y; v.z += o.z; v.w += o.w;
            }
            *reinterpret_cast<float4*>(cp + j) = v;
        }
    }
}

// ---------------------------------------------------------------------------
// Small-N GEMM (G2, N=48): BM=BN=64, BK=16 (from round 1).
// ---------------------------------------------------------------------------
#define BM 64
#define BN 64
#define BKK 16

__global__ __launch_bounds__(256)
void gemm64(const float* __restrict__ A, const float* __restrict__ B,
            float* __restrict__ C, int N, int K,
            int lda, int ldb, int ldc, int flipA, int accum)
{
    __shared__ float As[BKK][BM + 4];
    __shared__ float Bs[BKK][BN + 4];
    const int tid = threadIdx.x;
    const int gx = blockIdx.x, gy = blockIdx.y;
    const int row0 = gy * BM, col0 = gx * BN;
    const int ty = tid >> 4, tx = tid & 15;

    const int arow_l = tid >> 2;
    const int acol_l = (tid & 3) * 4;
    const int brow_l = tid >> 4;
    const int bcol_l = (tid & 15) * 4;

    int arow_g = row0 + arow_l;
    if (flipA) arow_g ^= (T_SEQ - 1);
    const float* Aptr = A + (size_t)arow_g * lda + acol_l;

    float acc[4][4] = {};

    for (int k0 = 0; k0 < K; k0 += BKK) {
        float4 av = *reinterpret_cast<const float4*>(Aptr + k0);
        As[acol_l + 0][arow_l] = av.x;
        As[acol_l + 1][arow_l] = av.y;
        As[acol_l + 2][arow_l] = av.z;
        As[acol_l + 3][arow_l] = av.w;

        int bn = col0 + bcol_l;
        const float* Bp = B + (size_t)(k0 + brow_l) * ldb + bn;
        float4 bv;
        if (bn + 3 < N) {
            bv = *reinterpret_cast<const float4*>(Bp);
        } else {
            bv.x = (bn + 0 < N) ? Bp[0] : 0.f;
            bv.y = (bn + 1 < N) ? Bp[1] : 0.f;
            bv.z = (bn + 2 < N) ? Bp[2] : 0.f;
            bv.w = (bn + 3 < N) ? Bp[3] : 0.f;
        }
        *reinterpret_cast<float4*>(&Bs[brow_l][bcol_l]) = bv;

        __syncthreads();
        #pragma unroll
        for (int k = 0; k < BKK; ++k) {
            float4 a4 = *reinterpret_cast<const float4*>(&As[k][ty * 4]);
            float4 b4 = *reinterpret_cast<const float4*>(&Bs[k][tx * 4]);
            float avv[4] = {a4.x, a4.y, a4.z, a4.w};
            float bvv[4] = {b4.x, b4.y, b4.z, b4.w};
            #pragma unroll
            for (int i = 0; i < 4; ++i)
                #pragma unroll
                for (int j = 0; j < 4; ++j)
                    acc[i][j] = fmaf(avv[i], bvv[j], acc[i][j]);
        }
        __syncthreads();
    }

    #pragma unroll
    for (int i = 0; i < 4; ++i) {
        int r = row0 + ty * 4 + i;
        #pragma unroll
        for (int j = 0; j < 4; ++j) {
            int c = col0 + tx * 4 + j;
            if (c < N) {
                size_t o = (size_t)r * ldc + c;
                C[o] = accum ? (C[o] + acc[i][j]) : acc[i][j];
            }
        }
    }
}

// ---------------------------------------------------------------------------
// Fuse W_out (512x256) @ merge_W[mrow0:mrow0+256, :] -> Wf (512x256)
// ---------------------------------------------------------------------------
__global__ __launch_bounds__(256)
void fusew_kernel(const float* __restrict__ W_out, const float* __restrict__ merge,
                  float* __restrict__ Wfused, int mrow0)
{
    int idx = blockIdx.x * 256 + threadIdx.x;
    int d = idx >> 8, j = idx & 255;
    float acc = 0.f;
    const float* wr = W_out + d * 256;
    const float* mc = merge + (size_t)mrow0 * 256 + j;
    #pragma unroll 4
    for (int m = 0; m < 256; ++m)
        acc = fmaf(wr[m], mc[(size_t)m * 256], acc);
    Wfused[idx] = acc;
}

// ---------------------------------------------------------------------------
// Causal depthwise conv (4 taps) + bias + silu.  8 outputs per thread.
// ---------------------------------------------------------------------------
__global__ __launch_bounds__(256)
void conv_kernel(const float* __restrict__ xz, const float* __restrict__ w,
                 const float* __restrict__ bias, float* __restrict__ xi)
{
    int idx = blockIdx.x * 256 + threadIdx.x;   // rb*512 + d
    int rb = idx >> 9, d = idx & 511;
    int r0 = rb * 8;
    int t0 = r0 & (T_SEQ - 1);                  // 8 | 4096 -> no batch straddle
    float w0 = w[d * 4 + 0], w1 = w[d * 4 + 1], w2 = w[d * 4 + 2], w3 = w[d * 4 + 3];
    float bs = bias[d];

    float xv[11];
    #pragma unroll
    for (int k = 0; k < 11; ++k) {
        int tt = t0 - 3 + k;
        xv[k] = (tt >= 0) ? xz[(size_t)(r0 - 3 + k) * 1024 + d] : 0.f;
    }
    #pragma unroll
    for (int j = 0; j < 8; ++j) {
        float acc = bs;
        acc = fmaf(w0, xv[j + 0], acc);
        acc = fmaf(w1, xv[j + 1], acc);
        acc = fmaf(w2, xv[j + 2], acc);
        acc = fmaf(w3, xv[j + 3], acc);
        xi[(size_t)(r0 + j) * 512 + d] = siluf(acc);
    }
}

// ---------------------------------------------------------------------------
// dt = softplus(xdbl[:, :16] @ W_dt + b_dt)
// ---------------------------------------------------------------------------
__global__ __launch_bounds__(256)
void dt_kernel(const float* __restrict__ xdbl, const float* __restrict__ W_dt,
               const float* __restrict__ b_dt, float* __restrict__ dt)
{
    int idx = blockIdx.x * 256 + threadIdx.x;
    int r = idx >> 9, n = idx & 511;
    const float* xr = xdbl + (size_t)r * 48;
    float acc = b_dt[n];
    #pragma unroll
    for (int k = 0; k < 16; ++k)
        acc = fmaf(xr[k], W_dt[k * 512 + n], acc);
    dt[idx] = softplusf(acc);
}

// ---------------------------------------------------------------------------
// Chunked scan, lane-per-channel layout: each thread owns one d, 16 states
// in registers.  bid = ((dir*2+b)*NCHUNK + chunk)*2 + half; d = half*256+tid.
// Summary: si = ((db*NCHUNK+chunk)*512 + d)*16 + n.
// ---------------------------------------------------------------------------
__global__ __launch_bounds__(256)
void scan_pass1(const float* __restrict__ dt_f, const float* __restrict__ dt_b,
                const float* __restrict__ xi_f, const float* __restrict__ xi_b,
                const float* __restrict__ xd_f, const float* __restrict__ xd_b,
                const float* __restrict__ Al_f, const float* __restrict__ Al_b,
                float* __restrict__ Acum, float* __restrict__ Hloc)
{
    __shared__ float Bsh[CLEN][16];
    int bid = blockIdx.x;
    int half = bid & 1;
    int tmp = bid >> 1;
    int chunk = tmp & (NCHUNK - 1);
    int db = tmp >> 6;
    int b = db & 1, dir = db >> 1;
    int d = half * 256 + threadIdx.x;

    const float* dt = dir ? dt_b : dt_f;
    const float* xi = dir ? xi_b : xi_f;
    const float* xd = dir ? xd_b : xd_f;
    const float* Al = dir ? Al_b : Al_f;

    float a[16];
    {
        const float4* ap = reinterpret_cast<const float4*>(Al + (size_t)d * 16);
        #pragma unroll
        for (int i = 0; i < 4; ++i) {
            float4 v = ap[i];
            a[4*i+0] = -expf(v.x); a[4*i+1] = -expf(v.y);
            a[4*i+2] = -expf(v.z); a[4*i+3] = -expf(v.w);
        }
    }

    size_t row0 = (size_t)b * T_SEQ + (size_t)chunk * CLEN;
    for (int i = threadIdx.x; i < CLEN * 16; i += 256) {
        int r = i >> 4, n = i & 15;
        Bsh[r][n] = xd[(row0 + r) * 48 + 16 + n];
    }
    __syncthreads();

    const float* dtp = dt + row0 * 512 + d;
    const float* xip = xi + row0 * 512 + d;

    float h[16] = {};
    float sumdt = 0.f;
    float dtv = dtp[0], xiv = xip[0];
    for (int t = 0; t < CLEN; ++t) {
        float dtn = 0.f, xin = 0.f;
        if (t + 1 < CLEN) { dtn = dtp[(t + 1) * 512]; xin = xip[(t + 1) * 512]; }
        float dbx = dtv * xiv;
        sumdt += dtv;
        float bn[16];
        {
            const float4* bq = reinterpret_cast<const float4*>(Bsh[t]);
            float4 b0 = bq[0], b1 = bq[1], b2 = bq[2], b3 = bq[3];
            bn[0]=b0.x; bn[1]=b0.y; bn[2]=b0.z; bn[3]=b0.w;
            bn[4]=b1.x; bn[5]=b1.y; bn[6]=b1.z; bn[7]=b1.w;
            bn[8]=b2.x; bn[9]=b2.y; bn[10]=b2.z; bn[11]=b2.w;
            bn[12]=b3.x; bn[13]=b3.y; bn[14]=b3.z; bn[15]=b3.w;
        }
        #pragma unroll
        for (int n = 0; n < 16; ++n) {
            float dA = __expf(dtv * a[n]);
            h[n] = fmaf(dA, h[n], dbx * bn[n]);
        }
        dtv = dtn; xiv = xin;
    }

    size_t si = ((size_t)((db * NCHUNK + chunk) * 512 + d)) * 16;
    float4* Ao = reinterpret_cast<float4*>(Acum + si);
    float4* Ho = reinterpret_cast<float4*>(Hloc + si);
    #pragma unroll
    for (int i = 0; i < 4; ++i) {
        Ao[i] = make_float4(__expf(a[4*i+0]*sumdt), __expf(a[4*i+1]*sumdt),
                            __expf(a[4*i+2]*sumdt), __expf(a[4*i+3]*sumdt));
        Ho[i] = make_float4(h[4*i+0], h[4*i+1], h[4*i+2], h[4*i+3]);
    }
}

// pass2: sequential scan over chunk summaries -> h_in per chunk.
__global__ __launch_bounds__(256)
void scan_pass2(const float* __restrict__ Acum, const float* __restrict__ Hloc,
                float* __restrict__ Hin)
{
    int tid = blockIdx.x * 256 + threadIdx.x;
    int db = tid >> 13;
    int dn = tid & 8191;
    size_t base = (size_t)db * NCHUNK * 8192 + dn;
    float h = 0.f;
    #pragma unroll 8
    for (int c = 0; c < NCHUNK; ++c) {
        size_t si = base + (size_t)c * 8192;
        Hin[si] = h;
        h = fmaf(Acum[si], h, Hloc[si]);
    }
}

// pass3: replay from h_in, emit y fused with gate:  y=(ys+xi*D)*silu(z)
__global__ __launch_bounds__(256)
void scan_pass3(const float* __restrict__ dt_f, const float* __restrict__ dt_b,
                const float* __restrict__ xi_f, const float* __restrict__ xi_b,
                const float* __restrict__ xd_f, const float* __restrict__ xd_b,
                const float* __restrict__ Al_f, const float* __restrict__ Al_b,
                const float* __restrict__ xz_f, const float* __restrict__ xz_b,
                const float* __restrict__ D_f, const float* __restrict__ D_b,
                const float* __restrict__ Hin,
                float* __restrict__ y_f, float* __restrict__ y_b)
{
    __shared__ float Bsh[CLEN][16];
    __shared__ float Csh[CLEN][16];
    int bid = blockIdx.x;
    int half = bid & 1;
    int tmp = bid >> 1;
    int chunk = tmp & (NCHUNK - 1);
    int db = tmp >> 6;
    int b = db & 1, dir = db >> 1;
    int d = half * 256 + threadIdx.x;

    const float* dt = dir ? dt_b : dt_f;
    const float* xi = dir ? xi_b : xi_f;
    const float* xd = dir ? xd_b : xd_f;
    const float* Al = dir ? Al_b : Al_f;
    const float* xz = dir ? xz_b : xz_f;
    const float* Dv = dir ? D_b  : D_f;
    float*       y  = dir ? y_b  : y_f;

    float a[16];
    {
        const float4* ap = reinterpret_cast<const float4*>(Al + (size_t)d * 16);
        #pragma unroll
        for (int i = 0; i < 4; ++i) {
            float4 v = ap[i];
            a[4*i+0] = -expf(v.x); a[4*i+1] = -expf(v.y);
            a[4*i+2] = -expf(v.z); a[4*i+3] = -expf(v.w);
        }
    }
    float Dd = Dv[d];

    size_t row0 = (size_t)b * T_SEQ + (size_t)chunk * CLEN;
    for (int i = threadIdx.x; i < CLEN * 32; i += 256) {
        int r = i >> 5, c = i & 31;
        float v = xd[(row0 + r) * 48 + 16 + c];
        if (c < 16) Bsh[r][c] = v; else Csh[r][c - 16] = v;
    }
    __syncthreads();

    float h[16];
    {
        size_t si = ((size_t)((db * NCHUNK + chunk) * 512 + d)) * 16;
        const float4* hp = reinterpret_cast<const float4*>(Hin + si);
        #pragma unroll
        for (int i = 0; i < 4; ++i) {
            float4 v = hp[i];
            h[4*i+0] = v.x; h[4*i+1] = v.y; h[4*i+2] = v.z; h[4*i+3] = v.w;
        }
    }

    const float* dtp = dt + row0 * 512 + d;
    const float* xip = xi + row0 * 512 + d;
    const float* zp  = xz + row0 * 1024 + 512 + d;
    float*       yp  = y  + row0 * 512 + d;

    float dtv = dtp[0], xiv = xip[0], zv = zp[0];
    for (int t = 0; t < CLEN; ++t) {
        float dtn = 0.f, xin = 0.f, zn = 0.f;
        if (t + 1 < CLEN) {
            dtn = dtp[(t + 1) * 512];
            xin = xip[(t + 1) * 512];
            zn  = zp[(t + 1) * 1024];
        }
        float dbx = dtv * xiv;
        float bn[16], cn[16];
        {
            const float4* bq = reinterpret_cast<const float4*>(Bsh[t]);
            float4 b0 = bq[0], b1 = bq[1], b2 = bq[2], b3 = bq[3];
            bn[0]=b0.x; bn[1]=b0.y; bn[2]=b0.z; bn[3]=b0.w;
            bn[4]=b1.x; bn[5]=b1.y; bn[6]=b1.z; bn[7]=b1.w;
            bn[8]=b2.x; bn[9]=b2.y; bn[10]=b2.z; bn[11]=b2.w;
            bn[12]=b3.x; bn[13]=b3.y; bn[14]=b3.z; bn[15]=b3.w;
            const float4* cq = reinterpret_cast<const float4*>(Csh[t]);
            float4 c0 = cq[0], c1 = cq[1], c2 = cq[2], c3 = cq[3];
            cn[0]=c0.x; cn[1]=c0.y; cn[2]=c0.z; cn[3]=c0.w;
            cn[4]=c1.x; cn[5]=c1.y; cn[6]=c1.z; cn[7]=c1.w;
            cn[8]=c2.x; cn[9]=c2.y; cn[10]=c2.z; cn[11]=c2.w;
            cn[12]=c3.x; cn[13]=c3.y; cn[14]=c3.z; cn[15]=c3.w;
        }
        float yacc = 0.f;
        #pragma unroll
        for (int n = 0; n < 16; ++n) {
            float dA = __expf(dtv * a[n]);
            h[n] = fmaf(dA, h[n], dbx * bn[n]);
            yacc = fmaf(h[n], cn[n], yacc);
        }
        yp[t * 512] = fmaf(xiv, Dd, yacc) * siluf(zv);
        dtv = dtn; xiv = xin; zv = zn;
    }
}

// ---------------------------------------------------------------------------
extern "C" void kernel_launch(void* const* d_in, const int* in_sizes, int n_in,
                              void* d_out, int out_size, void* d_ws, size_t ws_size,
                              hipStream_t stream)
{
    const float* x       = (const float*)d_in[0];
    const float* fW_in   = (const float*)d_in[1];
    const float* fconv_w = (const float*)d_in[2];
    const float* fconv_b = (const float*)d_in[3];
    const float* fW_x    = (const float*)d_in[4];
    const float* fW_dt   = (const float*)d_in[5];
    const float* fb_dt   = (const float*)d_in[6];
    const float* fA_log  = (const float*)d_in[7];
    const float* fD      = (const float*)d_in[8];
    const float* fW_out  = (const float*)d_in[9];
    const float* bW_in   = (const float*)d_in[10];
    const float* bconv_w = (const float*)d_in[11];
    const float* bconv_b = (const float*)d_in[12];
    const float* bW_x    = (const float*)d_in[13];
    const float* bW_dt   = (const float*)d_in[14];
    const float* bb_dt   = (const float*)d_in[15];
    const float* bA_log  = (const float*)d_in[16];
    const float* bD      = (const float*)d_in[17];
    const float* bW_out  = (const float*)d_in[18];
    const float* merge   = (const float*)d_in[19];
    float* out = (float*)d_out;

    char* ws = (char*)d_ws;
    float* xz_f = (float*)ws; ws += (size_t)ROWS * 1024 * 4;
    float* xz_b = (float*)ws; ws += (size_t)ROWS * 1024 * 4;
    float* xi_f = (float*)ws; ws += (size_t)ROWS * 512 * 4;
    float* xi_b = (float*)ws; ws += (size_t)ROWS * 512 * 4;
    float* xd_f = (float*)ws; ws += (size_t)ROWS * 48 * 4;
    float* xd_b = (float*)ws; ws += (size_t)ROWS * 48 * 4;
    float* dt_f = (float*)ws; ws += (size_t)ROWS * 512 * 4;
    float* dt_b = (float*)ws; ws += (size_t)ROWS * 512 * 4;
    float* y_f  = (float*)ws; ws += (size_t)ROWS * 512 * 4;
    float* y_b  = (float*)ws; ws += (size_t)ROWS * 512 * 4;
    float* Wf   = (float*)ws; ws += (size_t)512 * 256 * 4;
    float* Wb   = (float*)ws; ws += (size_t)512 * 256 * 4;
    float* Acum = (float*)ws; ws += (size_t)4 * NCHUNK * 8192 * 4;
    float* Hloc = (float*)ws; ws += (size_t)4 * NCHUNK * 8192 * 4;
    float* Hin  = (float*)ws; ws += (size_t)4 * NCHUNK * 8192 * 4;

    dim3 blk(256);

    // G0: fused output weights
    fusew_kernel<<<512, blk, 0, stream>>>(fW_out, merge, Wf, 0);
    fusew_kernel<<<512, blk, 0, stream>>>(bW_out, merge, Wb, 256);

    // G1: xz = x @ W_in (bw reads time-flipped x)   M=8192 N=1024 K=256
    dim3 g1(1024 / 128, ROWS / 128);
    gemm128<128, 8><<<g1, blk, 0, stream>>>(x, fW_in, xz_f, 256, 256, 1024, 1024, 0, 0);
    gemm128<128, 8><<<g1, blk, 0, stream>>>(x, bW_in, xz_b, 256, 256, 1024, 1024, 1, 0);

    // conv + silu (8 outputs/thread)
    int conv_blocks = ROWS / 8 * 512 / 256;
    conv_kernel<<<conv_blocks, blk, 0, stream>>>(xz_f, fconv_w, fconv_b, xi_f);
    conv_kernel<<<conv_blocks, blk, 0, stream>>>(xz_b, bconv_w, bconv_b, xi_b);

    // G2: xdbl = xi @ W_x  (N=48)
    dim3 g2(1, ROWS / BM);
    gemm64<<<g2, blk, 0, stream>>>(xi_f, fW_x, xd_f, 48, 512, 512, 48, 48, 0, 0);
    gemm64<<<g2, blk, 0, stream>>>(xi_b, bW_x, xd_b, 48, 512, 512, 48, 48, 0, 0);

    // G3: dt
    int pw_blocks = ROWS * 512 / 256;
    dt_kernel<<<pw_blocks, blk, 0, stream>>>(xd_f, fW_dt, fb_dt, dt_f);
    dt_kernel<<<pw_blocks, blk, 0, stream>>>(xd_b, bW_dt, bb_dt, dt_b);

    // chunked scan, lane-per-channel
    scan_pass1<<<512, blk, 0, stream>>>(dt_f, dt_b, xi_f, xi_b, xd_f, xd_b,
                                        fA_log, bA_log, Acum, Hloc);
    scan_pass2<<<128, blk, 0, stream>>>(Acum, Hloc, Hin);
    scan_pass3<<<512, blk, 0, stream>>>(dt_f, dt_b, xi_f, xi_b, xd_f, xd_b,
                                        fA_log, bA_log, xz_f, xz_b, fD, bD,
                                        Hin, y_f, y_b);

    // G5: out = ygate_f @ Wf + flip(ygate_b) @ Wb   M=8192 N=256 K=512
    dim3 g5(256 / 64, ROWS / 128);
    gemm128<64, 4><<<g5, blk, 0, stream>>>(y_f, Wf, out, 512, 512, 256, 256, 0, 0);
    gemm128<64, 4><<<g5, blk, 0, stream>>>(y_b, Wb, out, 512, 512, 256, 256, 1, 1);
}

// Round 4
// 283.465 us; speedup vs baseline: 7.5243x; 1.6245x over previous
//
#include <hip/hip_runtime.h>
#include <math.h>

#define T_SEQ 4096
#define ROWS 8192
#define NCHUNK 64
#define CLEN 64

typedef __attribute__((ext_vector_type(4))) float f32x4;
typedef __attribute__((ext_vector_type(8))) short s16x8;

__device__ __forceinline__ float siluf(float x) { return x / (1.f + __expf(-x)); }
__device__ __forceinline__ float softplusf(float x) {
    return fmaxf(x, 0.f) + log1pf(__expf(-fabsf(x)));
}
__device__ __forceinline__ ushort f2b(float f) {
    uint u = __float_as_uint(f);
    u += 0x7fffu + ((u >> 16) & 1u);
    return (ushort)(u >> 16);
}
__device__ __forceinline__ float b2f(ushort h) { return __uint_as_float(((uint)h) << 16); }

// ---------------------------------------------------------------------------
// fp32 -> bf16 bulk convert (8 elems/thread)
// ---------------------------------------------------------------------------
__global__ __launch_bounds__(256)
void cvt_bf16(const float* __restrict__ in, ushort* __restrict__ out)
{
    int i = blockIdx.x * 256 + threadIdx.x;
    const float4* p = reinterpret_cast<const float4*>(in) + (size_t)i * 2;
    float4 a = p[0], b = p[1];
    s16x8 v;
    v[0] = (short)f2b(a.x); v[1] = (short)f2b(a.y); v[2] = (short)f2b(a.z); v[3] = (short)f2b(a.w);
    v[4] = (short)f2b(b.x); v[5] = (short)f2b(b.y); v[6] = (short)f2b(b.z); v[7] = (short)f2b(b.w);
    *reinterpret_cast<s16x8*>(out + (size_t)i * 8) = v;
}

// ---------------------------------------------------------------------------
// W [Kdim][Ndim] fp32 -> WT [Ndim][Kdim] bf16   (Kdim multiple of 8, pow2/8)
// ---------------------------------------------------------------------------
__global__ __launch_bounds__(256)
void transpose_w(const float* __restrict__ W, ushort* __restrict__ WT, int Kdim, int Ndim)
{
    int idx = blockIdx.x * 256 + threadIdx.x;
    int kg8 = Kdim >> 3;
    if (idx >= Ndim * kg8) return;
    int n = idx / kg8, kg = idx - n * kg8;
    s16x8 v;
    #pragma unroll
    for (int i = 0; i < 8; ++i)
        v[i] = (short)f2b(W[(size_t)(kg * 8 + i) * Ndim + n]);
    *reinterpret_cast<s16x8*>(WT + (size_t)n * Kdim + kg * 8) = v;
}

// ---------------------------------------------------------------------------
// Fused+transposed output weights: WT[j][d] = sum_m W_out[d][m]*merge[mrow0+m][j]
// WT is [256][512] bf16 (BT layout for G5)
// ---------------------------------------------------------------------------
__global__ __launch_bounds__(256)
void fusewT(const float* __restrict__ W_out, const float* __restrict__ merge,
            ushort* __restrict__ WT, int mrow0)
{
    int idx = blockIdx.x * 256 + threadIdx.x;   // d*256 + j
    int dd = idx >> 8, j = idx & 255;
    float acc = 0.f;
    const float* wr = W_out + dd * 256;
    const float* mc = merge + (size_t)mrow0 * 256 + j;
    #pragma unroll 4
    for (int m = 0; m < 256; ++m)
        acc = fmaf(wr[m], mc[(size_t)m * 256], acc);
    WT[(size_t)j * 512 + dd] = f2b(acc);
}

// ---------------------------------------------------------------------------
// bf16 MFMA GEMM:  C[M x N] = sum_seg A_seg(bf16, MxK row-major, opt row-flip)
//                             @ BT_seg(bf16, [N][K])^T
// 256 thr = 4 waves (2x2), wave tile (BM/2)x(BN/2), 16x16x32 frags, BK=64.
// LDS frag-linear layout, slot XOR-swizzle: conflict-minimal reads+writes.
// zmode: blockIdx.z selects seg (independent outputs C0/C1); else loop nseg
// accumulating into one C.
// ---------------------------------------------------------------------------
template<int BM, int BN, bool OBF16>
__global__ __launch_bounds__(256)
void mfma_gemm(const ushort* __restrict__ A0, const ushort* __restrict__ A1,
               const ushort* __restrict__ B0, const ushort* __restrict__ B1,
               void* __restrict__ C0, void* __restrict__ C1,
               int K, int ldc, int flip0, int flip1, int zmode, int nseg)
{
    constexpr int AFR = BM / 16, BFR = BN / 16;
    constexpr int MF = BM / 32, NF = BN / 32;
    constexpr int ABYTES = 2 * AFR * 1024 + 64;
    constexpr int BBYTES = 2 * BFR * 1024 + 64;
    __shared__ char ldsc[ABYTES + BBYTES];

    const int tid = threadIdx.x;
    const int lane = tid & 63, wave = tid >> 6;
    const int wm = wave >> 1, wn = wave & 1;
    const int m0 = blockIdx.y * BM, n0 = blockIdx.x * BN;
    const int slotL = (lane * 16) ^ ((lane >> 4) << 5);

    f32x4 acc[MF][NF];
    #pragma unroll
    for (int i = 0; i < MF; ++i)
        #pragma unroll
        for (int j = 0; j < NF; ++j)
            acc[i][j] = (f32x4){0.f, 0.f, 0.f, 0.f};

    const int kg = tid & 7, kkw = kg >> 2, gw = kg & 3;
    const int sb = zmode ? blockIdx.z : 0;
    const int se = zmode ? sb + 1 : nseg;

    for (int s = sb; s < se; ++s) {
        const ushort* Ap = s ? A1 : A0;
        const ushort* Bp = s ? B1 : B0;
        const int flip = s ? flip1 : flip0;
        for (int k0 = 0; k0 < K; k0 += 64) {
            #pragma unroll
            for (int rd = 0; rd < BM / 32; ++rd) {
                int rl = rd * 32 + (tid >> 3);
                int rg = m0 + rl;
                if (flip) rg ^= (T_SEQ - 1);
                s16x8 v = *reinterpret_cast<const s16x8*>(Ap + (size_t)rg * K + k0 + kg * 8);
                int l2 = (rl & 15) | (gw << 4);
                int off = (kkw * AFR + (rl >> 4)) * 1024 + (kkw << 5) + ((l2 * 16) ^ (gw << 5));
                *reinterpret_cast<s16x8*>(ldsc + off) = v;
            }
            #pragma unroll
            for (int rd = 0; rd < BN / 32; ++rd) {
                int nl = rd * 32 + (tid >> 3);
                int ng = n0 + nl;
                s16x8 v = *reinterpret_cast<const s16x8*>(Bp + (size_t)ng * K + k0 + kg * 8);
                int l2 = (nl & 15) | (gw << 4);
                int off = ABYTES + (kkw * BFR + (nl >> 4)) * 1024 + (kkw << 5) + ((l2 * 16) ^ (gw << 5));
                *reinterpret_cast<s16x8*>(ldsc + off) = v;
            }
            __syncthreads();
            #pragma unroll
            for (int kk = 0; kk < 2; ++kk) {
                s16x8 af[MF], bfv[NF];
                #pragma unroll
                for (int i = 0; i < MF; ++i)
                    af[i] = *reinterpret_cast<const s16x8*>(
                        ldsc + (kk * AFR + wm * MF + i) * 1024 + (kk << 5) + slotL);
                #pragma unroll
                for (int j = 0; j < NF; ++j)
                    bfv[j] = *reinterpret_cast<const s16x8*>(
                        ldsc + ABYTES + (kk * BFR + wn * NF + j) * 1024 + (kk << 5) + slotL);
                #pragma unroll
                for (int i = 0; i < MF; ++i)
                    #pragma unroll
                    for (int j = 0; j < NF; ++j)
                        acc[i][j] = __builtin_amdgcn_mfma_f32_16x16x32_bf16(
                            af[i], bfv[j], acc[i][j], 0, 0, 0);
            }
            __syncthreads();
        }
    }

    void* Cv = (zmode && blockIdx.z) ? C1 : C0;
    #pragma unroll
    for (int i = 0; i < MF; ++i) {
        #pragma unroll
        for (int j = 0; j < NF; ++j) {
            int r0 = m0 + wm * (BM / 2) + i * 16 + ((lane >> 4) << 2);
            int c  = n0 + wn * (BN / 2) + j * 16 + (lane & 15);
            #pragma unroll
            for (int r = 0; r < 4; ++r) {
                size_t o = (size_t)(r0 + r) * ldc + c;
                if (OBF16) ((ushort*)Cv)[o] = f2b(acc[i][j][r]);
                else       ((float*)Cv)[o]  = acc[i][j][r];
            }
        }
    }
}

// ---------------------------------------------------------------------------
// Small-N fp32 GEMM (G2, N=48), bf16 A, f/b merged via blockIdx.z.
// ---------------------------------------------------------------------------
__global__ __launch_bounds__(256)
void gemm64m(const ushort* __restrict__ A0, const ushort* __restrict__ A1,
             const float* __restrict__ B0, const float* __restrict__ B1,
             float* __restrict__ C0, float* __restrict__ C1,
             int N, int K, int lda, int ldb, int ldc)
{
    const ushort* A = blockIdx.z ? A1 : A0;
    const float*  B = blockIdx.z ? B1 : B0;
    float*        C = blockIdx.z ? C1 : C0;

    __shared__ float As[16][64 + 4];
    __shared__ float Bs[16][64 + 4];
    const int tid = threadIdx.x;
    const int row0 = blockIdx.y * 64, col0 = blockIdx.x * 64;
    const int ty = tid >> 4, tx = tid & 15;

    const int arow_l = tid >> 2;
    const int acol_l = (tid & 3) * 4;
    const int brow_l = tid >> 4;
    const int bcol_l = (tid & 15) * 4;

    const ushort* Aptr = A + (size_t)(row0 + arow_l) * lda + acol_l;
    float acc[4][4] = {};

    for (int k0 = 0; k0 < K; k0 += 16) {
        ushort4 av = *reinterpret_cast<const ushort4*>(Aptr + k0);
        As[acol_l + 0][arow_l] = b2f(av.x);
        As[acol_l + 1][arow_l] = b2f(av.y);
        As[acol_l + 2][arow_l] = b2f(av.z);
        As[acol_l + 3][arow_l] = b2f(av.w);

        int bn = col0 + bcol_l;
        const float* Bp = B + (size_t)(k0 + brow_l) * ldb + bn;
        float4 bv;
        bv.x = (bn + 0 < N) ? Bp[0] : 0.f;
        bv.y = (bn + 1 < N) ? Bp[1] : 0.f;
        bv.z = (bn + 2 < N) ? Bp[2] : 0.f;
        bv.w = (bn + 3 < N) ? Bp[3] : 0.f;
        *reinterpret_cast<float4*>(&Bs[brow_l][bcol_l]) = bv;

        __syncthreads();
        #pragma unroll
        for (int k = 0; k < 16; ++k) {
            float4 a4 = *reinterpret_cast<const float4*>(&As[k][ty * 4]);
            float4 b4 = *reinterpret_cast<const float4*>(&Bs[k][tx * 4]);
            float avv[4] = {a4.x, a4.y, a4.z, a4.w};
            float bvv[4] = {b4.x, b4.y, b4.z, b4.w};
            #pragma unroll
            for (int i = 0; i < 4; ++i)
                #pragma unroll
                for (int j = 0; j < 4; ++j)
                    acc[i][j] = fmaf(avv[i], bvv[j], acc[i][j]);
        }
        __syncthreads();
    }

    #pragma unroll
    for (int i = 0; i < 4; ++i) {
        int r = row0 + ty * 4 + i;
        #pragma unroll
        for (int j = 0; j < 4; ++j) {
            int c = col0 + tx * 4 + j;
            if (c < N) C[(size_t)r * ldc + c] = acc[i][j];
        }
    }
}

// ---------------------------------------------------------------------------
// Causal depthwise conv (4 taps) + bias + silu, bf16 in/out, 8 rows/thread.
// ---------------------------------------------------------------------------
__global__ __launch_bounds__(256)
void conv_kernel(const ushort* __restrict__ xz, const float* __restrict__ w,
                 const float* __restrict__ bias, ushort* __restrict__ xi)
{
    int idx = blockIdx.x * 256 + threadIdx.x;   // rb*512 + d
    int rb = idx >> 9, d = idx & 511;
    int r0 = rb * 8;
    int t0 = r0 & (T_SEQ - 1);
    float w0 = w[d * 4 + 0], w1 = w[d * 4 + 1], w2 = w[d * 4 + 2], w3 = w[d * 4 + 3];
    float bs = bias[d];

    float xv[11];
    #pragma unroll
    for (int k = 0; k < 11; ++k) {
        int tt = t0 - 3 + k;
        xv[k] = (tt >= 0) ? b2f(xz[(size_t)(r0 - 3 + k) * 1024 + d]) : 0.f;
    }
    #pragma unroll
    for (int j = 0; j < 8; ++j) {
        float acc = bs;
        acc = fmaf(w0, xv[j + 0], acc);
        acc = fmaf(w1, xv[j + 1], acc);
        acc = fmaf(w2, xv[j + 2], acc);
        acc = fmaf(w3, xv[j + 3], acc);
        xi[(size_t)(r0 + j) * 512 + d] = f2b(siluf(acc));
    }
}

// ---------------------------------------------------------------------------
// Chunked scan.  Thread owns channel d, 16 states in regs.  dt recomputed
// in-kernel from LDS-staged xdbl (cols 0..15) @ W_dt col d + softplus.
// bid = ((dir*2+b)*NCHUNK + chunk)*2 + half; d = half*256 + tid.
// ---------------------------------------------------------------------------
__global__ __launch_bounds__(256)
void scan_pass1(const ushort* __restrict__ xi_f, const ushort* __restrict__ xi_b,
                const float* __restrict__ xd_f, const float* __restrict__ xd_b,
                const float* __restrict__ Wdt_f, const float* __restrict__ Wdt_b,
                const float* __restrict__ bdt_f, const float* __restrict__ bdt_b,
                const float* __restrict__ Al_f, const float* __restrict__ Al_b,
                float* __restrict__ Acum, float* __restrict__ Hloc)
{
    __shared__ float Dsh[CLEN][16];
    __shared__ float Bsh[CLEN][16];
    int bid = blockIdx.x;
    int half = bid & 1;
    int tmp = bid >> 1;
    int chunk = tmp & (NCHUNK - 1);
    int db = tmp >> 6;
    int b = db & 1, dir = db >> 1;
    int d = half * 256 + threadIdx.x;

    const ushort* xi = dir ? xi_b : xi_f;
    const float* xd  = dir ? xd_b : xd_f;
    const float* Wdt = dir ? Wdt_b : Wdt_f;
    const float* bdt = dir ? bdt_b : bdt_f;
    const float* Al  = dir ? Al_b : Al_f;

    float a[16];
    {
        const float4* ap = reinterpret_cast<const float4*>(Al + (size_t)d * 16);
        #pragma unroll
        for (int i = 0; i < 4; ++i) {
            float4 v = ap[i];
            a[4*i+0] = -expf(v.x); a[4*i+1] = -expf(v.y);
            a[4*i+2] = -expf(v.z); a[4*i+3] = -expf(v.w);
        }
    }
    float wdt[16];
    #pragma unroll
    for (int k = 0; k < 16; ++k) wdt[k] = Wdt[k * 512 + d];
    float bd = bdt[d];

    size_t row0 = (size_t)b * T_SEQ + (size_t)chunk * CLEN;
    for (int i = threadIdx.x; i < CLEN * 32; i += 256) {
        int r = i >> 5, c = i & 31;
        float v = xd[(row0 + r) * 48 + c];
        if (c < 16) Dsh[r][c] = v; else Bsh[r][c - 16] = v;
    }
    __syncthreads();

    const ushort* xip = xi + row0 * 512 + d;
    float h[16] = {};
    float sumdt = 0.f;
    #pragma unroll 2
    for (int t = 0; t < CLEN; ++t) {
        float dv[16], bn[16];
        {
            const float4* dq = reinterpret_cast<const float4*>(Dsh[t]);
            const float4* bq = reinterpret_cast<const float4*>(Bsh[t]);
            #pragma unroll
            for (int q = 0; q < 4; ++q) {
                float4 dd = dq[q], bb = bq[q];
                dv[4*q+0]=dd.x; dv[4*q+1]=dd.y; dv[4*q+2]=dd.z; dv[4*q+3]=dd.w;
                bn[4*q+0]=bb.x; bn[4*q+1]=bb.y; bn[4*q+2]=bb.z; bn[4*q+3]=bb.w;
            }
        }
        float arg = bd;
        #pragma unroll
        for (int k = 0; k < 16; ++k) arg = fmaf(dv[k], wdt[k], arg);
        float dtv = softplusf(arg);
        float xiv = b2f(xip[(size_t)t * 512]);
        float dbx = dtv * xiv;
        sumdt += dtv;
        #pragma unroll
        for (int n = 0; n < 16; ++n) {
            float dA = __expf(dtv * a[n]);
            h[n] = fmaf(dA, h[n], dbx * bn[n]);
        }
    }

    size_t si = ((size_t)((db * NCHUNK + chunk) * 512 + d)) * 16;
    float4* Ao = reinterpret_cast<float4*>(Acum + si);
    float4* Ho = reinterpret_cast<float4*>(Hloc + si);
    #pragma unroll
    for (int i = 0; i < 4; ++i) {
        Ao[i] = make_float4(__expf(a[4*i+0]*sumdt), __expf(a[4*i+1]*sumdt),
                            __expf(a[4*i+2]*sumdt), __expf(a[4*i+3]*sumdt));
        Ho[i] = make_float4(h[4*i+0], h[4*i+1], h[4*i+2], h[4*i+3]);
    }
}

__global__ __launch_bounds__(256)
void scan_pass2(const float* __restrict__ Acum, const float* __restrict__ Hloc,
                float* __restrict__ Hin)
{
    int tid = blockIdx.x * 256 + threadIdx.x;
    int db = tid >> 13;
    int dn = tid & 8191;
    size_t base = (size_t)db * NCHUNK * 8192 + dn;
    float h = 0.f;
    #pragma unroll 8
    for (int c = 0; c < NCHUNK; ++c) {
        size_t si = base + (size_t)c * 8192;
        Hin[si] = h;
        h = fmaf(Acum[si], h, Hloc[si]);
    }
}

// pass3: replay from h_in, fused gate, bf16 y out.
__global__ __launch_bounds__(256)
void scan_pass3(const ushort* __restrict__ xi_f, const ushort* __restrict__ xi_b,
                const float* __restrict__ xd_f, const float* __restrict__ xd_b,
                const float* __restrict__ Wdt_f, const float* __restrict__ Wdt_b,
                const float* __restrict__ bdt_f, const float* __restrict__ bdt_b,
                const float* __restrict__ Al_f, const float* __restrict__ Al_b,
                const ushort* __restrict__ xz_f, const ushort* __restrict__ xz_b,
                const float* __restrict__ D_f, const float* __restrict__ D_b,
                const float* __restrict__ Hin,
                ushort* __restrict__ y_f, ushort* __restrict__ y_b)
{
    __shared__ float Dsh[CLEN][16];
    __shared__ float Bsh[CLEN][16];
    __shared__ float Csh[CLEN][16];
    int bid = blockIdx.x;
    int half = bid & 1;
    int tmp = bid >> 1;
    int chunk = tmp & (NCHUNK - 1);
    int db = tmp >> 6;
    int b = db & 1, dir = db >> 1;
    int d = half * 256 + threadIdx.x;

    const ushort* xi = dir ? xi_b : xi_f;
    const float* xd  = dir ? xd_b : xd_f;
    const float* Wdt = dir ? Wdt_b : Wdt_f;
    const float* bdt = dir ? bdt_b : bdt_f;
    const float* Al  = dir ? Al_b : Al_f;
    const ushort* xz = dir ? xz_b : xz_f;
    const float* Dv  = dir ? D_b  : D_f;
    ushort*      y   = dir ? y_b  : y_f;

    float a[16];
    {
        const float4* ap = reinterpret_cast<const float4*>(Al + (size_t)d * 16);
        #pragma unroll
        for (int i = 0; i < 4; ++i) {
            float4 v = ap[i];
            a[4*i+0] = -expf(v.x); a[4*i+1] = -expf(v.y);
            a[4*i+2] = -expf(v.z); a[4*i+3] = -expf(v.w);
        }
    }
    float wdt[16];
    #pragma unroll
    for (int k = 0; k < 16; ++k) wdt[k] = Wdt[k * 512 + d];
    float bd = bdt[d];
    float Dd = Dv[d];

    size_t row0 = (size_t)b * T_SEQ + (size_t)chunk * CLEN;
    for (int i = threadIdx.x; i < CLEN * 48; i += 256) {
        int r = i / 48, c = i - r * 48;
        float v = xd[(row0 + r) * 48 + c];
        if (c < 16) Dsh[r][c] = v;
        else if (c < 32) Bsh[r][c - 16] = v;
        else Csh[r][c - 32] = v;
    }
    __syncthreads();

    float h[16];
    {
        size_t si = ((size_t)((db * NCHUNK + chunk) * 512 + d)) * 16;
        const float4* hp = reinterpret_cast<const float4*>(Hin + si);
        #pragma unroll
        for (int i = 0; i < 4; ++i) {
            float4 v = hp[i];
            h[4*i+0] = v.x; h[4*i+1] = v.y; h[4*i+2] = v.z; h[4*i+3] = v.w;
        }
    }

    const ushort* xip = xi + row0 * 512 + d;
    const ushort* zp  = xz + row0 * 1024 + 512 + d;
    ushort*       yp  = y  + row0 * 512 + d;

    #pragma unroll 2
    for (int t = 0; t < CLEN; ++t) {
        float dv[16], bn[16], cn[16];
        {
            const float4* dq = reinterpret_cast<const float4*>(Dsh[t]);
            const float4* bq = reinterpret_cast<const float4*>(Bsh[t]);
            const float4* cq = reinterpret_cast<const float4*>(Csh[t]);
            #pragma unroll
            for (int q = 0; q < 4; ++q) {
                float4 dd = dq[q], bb = bq[q], cc = cq[q];
                dv[4*q+0]=dd.x; dv[4*q+1]=dd.y; dv[4*q+2]=dd.z; dv[4*q+3]=dd.w;
                bn[4*q+0]=bb.x; bn[4*q+1]=bb.y; bn[4*q+2]=bb.z; bn[4*q+3]=bb.w;
                cn[4*q+0]=cc.x; cn[4*q+1]=cc.y; cn[4*q+2]=cc.z; cn[4*q+3]=cc.w;
            }
        }
        float arg = bd;
        #pragma unroll
        for (int k = 0; k < 16; ++k) arg = fmaf(dv[k], wdt[k], arg);
        float dtv = softplusf(arg);
        float xiv = b2f(xip[(size_t)t * 512]);
        float zv  = b2f(zp[(size_t)t * 1024]);
        float dbx = dtv * xiv;
        float yacc = 0.f;
        #pragma unroll
        for (int n = 0; n < 16; ++n) {
            float dA = __expf(dtv * a[n]);
            h[n] = fmaf(dA, h[n], dbx * bn[n]);
            yacc = fmaf(h[n], cn[n], yacc);
        }
        yp[(size_t)t * 512] = f2b(fmaf(xiv, Dd, yacc) * siluf(zv));
    }
}

// ---------------------------------------------------------------------------
extern "C" void kernel_launch(void* const* d_in, const int* in_sizes, int n_in,
                              void* d_out, int out_size, void* d_ws, size_t ws_size,
                              hipStream_t stream)
{
    const float* x       = (const float*)d_in[0];
    const float* fW_in   = (const float*)d_in[1];
    const float* fconv_w = (const float*)d_in[2];
    const float* fconv_b = (const float*)d_in[3];
    const float* fW_x    = (const float*)d_in[4];
    const float* fW_dt   = (const float*)d_in[5];
    const float* fb_dt   = (const float*)d_in[6];
    const float* fA_log  = (const float*)d_in[7];
    const float* fD      = (const float*)d_in[8];
    const float* fW_out  = (const float*)d_in[9];
    const float* bW_in   = (const float*)d_in[10];
    const float* bconv_w = (const float*)d_in[11];
    const float* bconv_b = (const float*)d_in[12];
    const float* bW_x    = (const float*)d_in[13];
    const float* bW_dt   = (const float*)d_in[14];
    const float* bb_dt   = (const float*)d_in[15];
    const float* bA_log  = (const float*)d_in[16];
    const float* bD      = (const float*)d_in[17];
    const float* bW_out  = (const float*)d_in[18];
    const float* merge   = (const float*)d_in[19];
    float* out = (float*)d_out;

    char* ws = (char*)d_ws;
    ushort* xbh    = (ushort*)ws; ws += (size_t)ROWS * 256 * 2;
    ushort* WinT_f = (ushort*)ws; ws += (size_t)1024 * 256 * 2;
    ushort* WinT_b = (ushort*)ws; ws += (size_t)1024 * 256 * 2;
    ushort* WfT    = (ushort*)ws; ws += (size_t)256 * 512 * 2;
    ushort* WbT    = (ushort*)ws; ws += (size_t)256 * 512 * 2;
    ushort* xz_f   = (ushort*)ws; ws += (size_t)ROWS * 1024 * 2;
    ushort* xz_b   = (ushort*)ws; ws += (size_t)ROWS * 1024 * 2;
    ushort* xi_f   = (ushort*)ws; ws += (size_t)ROWS * 512 * 2;
    ushort* xi_b   = (ushort*)ws; ws += (size_t)ROWS * 512 * 2;
    ushort* y_f    = (ushort*)ws; ws += (size_t)ROWS * 512 * 2;
    ushort* y_b    = (ushort*)ws; ws += (size_t)ROWS * 512 * 2;
    float*  xd_f   = (float*)ws;  ws += (size_t)ROWS * 48 * 4;
    float*  xd_b   = (float*)ws;  ws += (size_t)ROWS * 48 * 4;
    float*  Acum   = (float*)ws;  ws += (size_t)4 * NCHUNK * 8192 * 4;
    float*  Hloc   = (float*)ws;  ws += (size_t)4 * NCHUNK * 8192 * 4;
    float*  Hin    = (float*)ws;  ws += (size_t)4 * NCHUNK * 8192 * 4;

    dim3 blk(256);

    // prep: bf16 conversions / transposes / fused output weights
    cvt_bf16<<<1024, blk, 0, stream>>>(x, xbh);                        // 2M elems
    transpose_w<<<128, blk, 0, stream>>>(fW_in, WinT_f, 256, 1024);
    transpose_w<<<128, blk, 0, stream>>>(bW_in, WinT_b, 256, 1024);
    fusewT<<<512, blk, 0, stream>>>(fW_out, merge, WfT, 0);
    fusewT<<<512, blk, 0, stream>>>(bW_out, merge, WbT, 256);

    // G1: xz = x @ W_in, both dirs in one launch (z picks dir; b flips rows)
    mfma_gemm<128, 128, true><<<dim3(8, 64, 2), blk, 0, stream>>>(
        xbh, xbh, WinT_f, WinT_b, xz_f, xz_b, 256, 1024, 0, 1, 1, 1);

    // conv + silu
    conv_kernel<<<2048, blk, 0, stream>>>(xz_f, fconv_w, fconv_b, xi_f);
    conv_kernel<<<2048, blk, 0, stream>>>(xz_b, bconv_w, bconv_b, xi_b);

    // G2: xdbl = xi @ W_x (N=48), merged dirs
    gemm64m<<<dim3(1, 128, 2), blk, 0, stream>>>(xi_f, xi_b, fW_x, bW_x,
                                                 xd_f, xd_b, 48, 512, 512, 48, 48);

    // chunked scan (dt recomputed in-kernel)
    scan_pass1<<<512, blk, 0, stream>>>(xi_f, xi_b, xd_f, xd_b, fW_dt, bW_dt,
                                        fb_dt, bb_dt, fA_log, bA_log, Acum, Hloc);
    scan_pass2<<<128, blk, 0, stream>>>(Acum, Hloc, Hin);
    scan_pass3<<<512, blk, 0, stream>>>(xi_f, xi_b, xd_f, xd_b, fW_dt, bW_dt,
                                        fb_dt, bb_dt, fA_log, bA_log, xz_f, xz_b,
                                        fD, bD, Hin, y_f, y_b);

    // G5: out = y_f @ WfT^T + flip(y_b) @ WbT^T  (K-concat, one pass)
    mfma_gemm<64, 64, false><<<dim3(4, 128, 1), blk, 0, stream>>>(
        y_f, y_b, WfT, WbT, out, out, 512, 256, 0, 1, 0, 2);
}

// Round 5
// 249.125 us; speedup vs baseline: 8.5615x; 1.1378x over previous
//
#include <hip/hip_runtime.h>
#include <math.h>

#define T_SEQ 4096
#define ROWS 8192
#define NCHUNK 128
#define CLEN 32

typedef __attribute__((ext_vector_type(4))) float f32x4;
typedef __attribute__((ext_vector_type(8))) short s16x8;

__device__ __forceinline__ float siluf(float x) { return x / (1.f + __expf(-x)); }
__device__ __forceinline__ float softplusf(float x) {
    return fmaxf(x, 0.f) + log1pf(__expf(-fabsf(x)));
}
__device__ __forceinline__ ushort f2b(float f) {
    uint u = __float_as_uint(f);
    u += 0x7fffu + ((u >> 16) & 1u);
    return (ushort)(u >> 16);
}
__device__ __forceinline__ float b2f(ushort h) { return __uint_as_float(((uint)h) << 16); }

// ---------------------------------------------------------------------------
// fp32 -> bf16 bulk convert (8 elems/thread)
// ---------------------------------------------------------------------------
__global__ __launch_bounds__(256)
void cvt_bf16(const float* __restrict__ in, ushort* __restrict__ out)
{
    int i = blockIdx.x * 256 + threadIdx.x;
    const float4* p = reinterpret_cast<const float4*>(in) + (size_t)i * 2;
    float4 a = p[0], b = p[1];
    s16x8 v;
    v[0] = (short)f2b(a.x); v[1] = (short)f2b(a.y); v[2] = (short)f2b(a.z); v[3] = (short)f2b(a.w);
    v[4] = (short)f2b(b.x); v[5] = (short)f2b(b.y); v[6] = (short)f2b(b.z); v[7] = (short)f2b(b.w);
    *reinterpret_cast<s16x8*>(out + (size_t)i * 8) = v;
}

// ---------------------------------------------------------------------------
// W [Kdim][Ndim] fp32 -> WT [Ndim][Kdim] bf16
// ---------------------------------------------------------------------------
__global__ __launch_bounds__(256)
void transpose_w(const float* __restrict__ W, ushort* __restrict__ WT, int Kdim, int Ndim)
{
    int idx = blockIdx.x * 256 + threadIdx.x;
    int kg8 = Kdim >> 3;
    if (idx >= Ndim * kg8) return;
    int n = idx / kg8, kg = idx - n * kg8;
    s16x8 v;
    #pragma unroll
    for (int i = 0; i < 8; ++i)
        v[i] = (short)f2b(W[(size_t)(kg * 8 + i) * Ndim + n]);
    *reinterpret_cast<s16x8*>(WT + (size_t)n * Kdim + kg * 8) = v;
}

// ---------------------------------------------------------------------------
// Fused+transposed output weights: WT[j][d] = sum_m W_out[d][m]*merge[mrow0+m][j]
// ---------------------------------------------------------------------------
__global__ __launch_bounds__(256)
void fusewT(const float* __restrict__ W_out, const float* __restrict__ merge,
            ushort* __restrict__ WT, int mrow0)
{
    int idx = blockIdx.x * 256 + threadIdx.x;   // d*256 + j
    int dd = idx >> 8, j = idx & 255;
    float acc = 0.f;
    const float* wr = W_out + dd * 256;
    const float* mc = merge + (size_t)mrow0 * 256 + j;
    #pragma unroll 4
    for (int m = 0; m < 256; ++m)
        acc = fmaf(wr[m], mc[(size_t)m * 256], acc);
    WT[(size_t)j * 512 + dd] = f2b(acc);
}

// ---------------------------------------------------------------------------
// Composed dt weight: WT[n][k] = sum_j W_x[k][j] * W_dt[j][n]  (bf16, [512][512])
// ---------------------------------------------------------------------------
__global__ __launch_bounds__(256)
void wcompT(const float* __restrict__ Wx, const float* __restrict__ Wdt,
            ushort* __restrict__ WT)
{
    int idx = blockIdx.x * 256 + threadIdx.x;   // n*64 + kg
    int n = idx >> 6, kg = idx & 63;
    s16x8 v;
    #pragma unroll
    for (int i = 0; i < 8; ++i) {
        int k = kg * 8 + i;
        float acc = 0.f;
        #pragma unroll
        for (int j = 0; j < 16; ++j)
            acc = fmaf(Wx[k * 48 + j], Wdt[j * 512 + n], acc);
        v[i] = (short)f2b(acc);
    }
    *reinterpret_cast<s16x8*>(WT + (size_t)n * 512 + kg * 8) = v;
}

// ---------------------------------------------------------------------------
// bf16 MFMA GEMM:  C = sum_seg A_seg(bf16 MxK, opt row-flip) @ BT_seg([N][K])^T
// 4 waves (2x2), wave tile (BM/2)x(BN/2), 16x16x32 frags, BK=64.
// EPI: 0 = f32 store, 1 = bf16 store, 2 = softplus(acc + bias[col]) f32 store.
// ---------------------------------------------------------------------------
template<int BM, int BN, int EPI>
__global__ __launch_bounds__(256)
void mfma_gemm(const ushort* __restrict__ A0, const ushort* __restrict__ A1,
               const ushort* __restrict__ B0, const ushort* __restrict__ B1,
               void* __restrict__ C0, void* __restrict__ C1,
               const float* __restrict__ bias0, const float* __restrict__ bias1,
               int K, int ldc, int flip0, int flip1, int zmode, int nseg)
{
    constexpr int AFR = BM / 16, BFR = BN / 16;
    constexpr int MF = BM / 32, NF = BN / 32;
    constexpr int ABYTES = 2 * AFR * 1024 + 64;
    constexpr int BBYTES = 2 * BFR * 1024 + 64;
    __shared__ char ldsc[ABYTES + BBYTES];

    const int tid = threadIdx.x;
    const int lane = tid & 63, wave = tid >> 6;
    const int wm = wave >> 1, wn = wave & 1;
    const int m0 = blockIdx.y * BM, n0 = blockIdx.x * BN;
    const int slotL = (lane * 16) ^ ((lane >> 4) << 5);

    f32x4 acc[MF][NF];
    #pragma unroll
    for (int i = 0; i < MF; ++i)
        #pragma unroll
        for (int j = 0; j < NF; ++j)
            acc[i][j] = (f32x4){0.f, 0.f, 0.f, 0.f};

    const int kg = tid & 7, kkw = kg >> 2, gw = kg & 3;
    const int sb = zmode ? blockIdx.z : 0;
    const int se = zmode ? sb + 1 : nseg;

    for (int s = sb; s < se; ++s) {
        const ushort* Ap = s ? A1 : A0;
        const ushort* Bp = s ? B1 : B0;
        const int flip = s ? flip1 : flip0;
        for (int k0 = 0; k0 < K; k0 += 64) {
            #pragma unroll
            for (int rd = 0; rd < BM / 32; ++rd) {
                int rl = rd * 32 + (tid >> 3);
                int rg = m0 + rl;
                if (flip) rg ^= (T_SEQ - 1);
                s16x8 v = *reinterpret_cast<const s16x8*>(Ap + (size_t)rg * K + k0 + kg * 8);
                int l2 = (rl & 15) | (gw << 4);
                int off = (kkw * AFR + (rl >> 4)) * 1024 + (kkw << 5) + ((l2 * 16) ^ (gw << 5));
                *reinterpret_cast<s16x8*>(ldsc + off) = v;
            }
            #pragma unroll
            for (int rd = 0; rd < BN / 32; ++rd) {
                int nl = rd * 32 + (tid >> 3);
                int ng = n0 + nl;
                s16x8 v = *reinterpret_cast<const s16x8*>(Bp + (size_t)ng * K + k0 + kg * 8);
                int l2 = (nl & 15) | (gw << 4);
                int off = ABYTES + (kkw * BFR + (nl >> 4)) * 1024 + (kkw << 5) + ((l2 * 16) ^ (gw << 5));
                *reinterpret_cast<s16x8*>(ldsc + off) = v;
            }
            __syncthreads();
            #pragma unroll
            for (int kk = 0; kk < 2; ++kk) {
                s16x8 af[MF], bfv[NF];
                #pragma unroll
                for (int i = 0; i < MF; ++i)
                    af[i] = *reinterpret_cast<const s16x8*>(
                        ldsc + (kk * AFR + wm * MF + i) * 1024 + (kk << 5) + slotL);
                #pragma unroll
                for (int j = 0; j < NF; ++j)
                    bfv[j] = *reinterpret_cast<const s16x8*>(
                        ldsc + ABYTES + (kk * BFR + wn * NF + j) * 1024 + (kk << 5) + slotL);
                #pragma unroll
                for (int i = 0; i < MF; ++i)
                    #pragma unroll
                    for (int j = 0; j < NF; ++j)
                        acc[i][j] = __builtin_amdgcn_mfma_f32_16x16x32_bf16(
                            af[i], bfv[j], acc[i][j], 0, 0, 0);
            }
            __syncthreads();
        }
    }

    void* Cv = (zmode && blockIdx.z) ? C1 : C0;
    const float* bias = (zmode && blockIdx.z) ? bias1 : bias0;
    #pragma unroll
    for (int i = 0; i < MF; ++i) {
        #pragma unroll
        for (int j = 0; j < NF; ++j) {
            int r0 = m0 + wm * (BM / 2) + i * 16 + ((lane >> 4) << 2);
            int c  = n0 + wn * (BN / 2) + j * 16 + (lane & 15);
            float bv = (EPI == 2) ? bias[c] : 0.f;
            #pragma unroll
            for (int r = 0; r < 4; ++r) {
                size_t o = (size_t)(r0 + r) * ldc + c;
                if (EPI == 1)      ((ushort*)Cv)[o] = f2b(acc[i][j][r]);
                else if (EPI == 2) ((float*)Cv)[o]  = softplusf(acc[i][j][r] + bv);
                else               ((float*)Cv)[o]  = acc[i][j][r];
            }
        }
    }
}

// ---------------------------------------------------------------------------
// Small-N fp32 GEMM (B/C proj, N=32), bf16 A, f/b merged via blockIdx.z.
// ---------------------------------------------------------------------------
__global__ __launch_bounds__(256)
void gemm64m(const ushort* __restrict__ A0, const ushort* __restrict__ A1,
             const float* __restrict__ B0, const float* __restrict__ B1,
             float* __restrict__ C0, float* __restrict__ C1,
             int N, int K, int lda, int ldb, int ldc)
{
    const ushort* A = blockIdx.z ? A1 : A0;
    const float*  B = blockIdx.z ? B1 : B0;
    float*        C = blockIdx.z ? C1 : C0;

    __shared__ float As[16][64 + 4];
    __shared__ float Bs[16][64 + 4];
    const int tid = threadIdx.x;
    const int row0 = blockIdx.y * 64, col0 = blockIdx.x * 64;
    const int ty = tid >> 4, tx = tid & 15;

    const int arow_l = tid >> 2;
    const int acol_l = (tid & 3) * 4;
    const int brow_l = tid >> 4;
    const int bcol_l = (tid & 15) * 4;

    const ushort* Aptr = A + (size_t)(row0 + arow_l) * lda + acol_l;
    float acc[4][4] = {};

    for (int k0 = 0; k0 < K; k0 += 16) {
        ushort4 av = *reinterpret_cast<const ushort4*>(Aptr + k0);
        As[acol_l + 0][arow_l] = b2f(av.x);
        As[acol_l + 1][arow_l] = b2f(av.y);
        As[acol_l + 2][arow_l] = b2f(av.z);
        As[acol_l + 3][arow_l] = b2f(av.w);

        int bn = col0 + bcol_l;
        const float* Bp = B + (size_t)(k0 + brow_l) * ldb + bn;
        float4 bv;
        bv.x = (bn + 0 < N) ? Bp[0] : 0.f;
        bv.y = (bn + 1 < N) ? Bp[1] : 0.f;
        bv.z = (bn + 2 < N) ? Bp[2] : 0.f;
        bv.w = (bn + 3 < N) ? Bp[3] : 0.f;
        *reinterpret_cast<float4*>(&Bs[brow_l][bcol_l]) = bv;

        __syncthreads();
        #pragma unroll
        for (int k = 0; k < 16; ++k) {
            float4 a4 = *reinterpret_cast<const float4*>(&As[k][ty * 4]);
            float4 b4 = *reinterpret_cast<const float4*>(&Bs[k][tx * 4]);
            float avv[4] = {a4.x, a4.y, a4.z, a4.w};
            float bvv[4] = {b4.x, b4.y, b4.z, b4.w};
            #pragma unroll
            for (int i = 0; i < 4; ++i)
                #pragma unroll
                for (int j = 0; j < 4; ++j)
                    acc[i][j] = fmaf(avv[i], bvv[j], acc[i][j]);
        }
        __syncthreads();
    }

    #pragma unroll
    for (int i = 0; i < 4; ++i) {
        int r = row0 + ty * 4 + i;
        #pragma unroll
        for (int j = 0; j < 4; ++j) {
            int c = col0 + tx * 4 + j;
            if (c < N) C[(size_t)r * ldc + c] = acc[i][j];
        }
    }
}

// ---------------------------------------------------------------------------
// Causal depthwise conv (4 taps) + bias + silu, bf16 in/out, 8 rows/thread.
// Both directions in one launch (2048 blocks each).
// ---------------------------------------------------------------------------
__global__ __launch_bounds__(256)
void conv_kernel(const ushort* __restrict__ xz_f, const ushort* __restrict__ xz_b,
                 const float* __restrict__ w_f, const float* __restrict__ w_b,
                 const float* __restrict__ bias_f, const float* __restrict__ bias_b,
                 ushort* __restrict__ xi_f, ushort* __restrict__ xi_b)
{
    int gid = blockIdx.x;
    int dir = gid >> 11;
    const ushort* xz  = dir ? xz_b : xz_f;
    const float*  w   = dir ? w_b : w_f;
    const float*  bia = dir ? bias_b : bias_f;
    ushort*       xi  = dir ? xi_b : xi_f;

    int idx = (gid & 2047) * 256 + threadIdx.x;   // rb*512 + d
    int rb = idx >> 9, d = idx & 511;
    int r0 = rb * 8;
    int t0 = r0 & (T_SEQ - 1);
    float w0 = w[d * 4 + 0], w1 = w[d * 4 + 1], w2 = w[d * 4 + 2], w3 = w[d * 4 + 3];
    float bs = bia[d];

    float xv[11];
    #pragma unroll
    for (int k = 0; k < 11; ++k) {
        int tt = t0 - 3 + k;
        xv[k] = (tt >= 0) ? b2f(xz[(size_t)(r0 - 3 + k) * 1024 + d]) : 0.f;
    }
    #pragma unroll
    for (int j = 0; j < 8; ++j) {
        float acc = bs;
        acc = fmaf(w0, xv[j + 0], acc);
        acc = fmaf(w1, xv[j + 1], acc);
        acc = fmaf(w2, xv[j + 2], acc);
        acc = fmaf(w3, xv[j + 3], acc);
        xi[(size_t)(r0 + j) * 512 + d] = f2b(siluf(acc));
    }
}

// ---------------------------------------------------------------------------
// Chunked scan.  Thread owns channel d (16 states in regs); dt precomputed.
// bid = ((db*NCHUNK + chunk)*2 + half); d = half*256 + tid.
// Fast path: a[n] == (n+1)*a[0]  =>  dA_n = q^(n+1), q = exp(dt*a0).
// ---------------------------------------------------------------------------
__device__ __forceinline__ void scan_head(int bid, int tid,
    int& db, int& b, int& dir, int& chunk, int& d, size_t& row0)
{
    int half = bid & 1;
    int tmp = bid >> 1;
    chunk = tmp & (NCHUNK - 1);
    db = tmp >> 7;
    b = db & 1; dir = db >> 1;
    d = half * 256 + tid;
    row0 = (size_t)b * T_SEQ + (size_t)chunk * CLEN;
}

__device__ __forceinline__ void load_a16(const float* __restrict__ Al, int d,
                                         float* a, bool& fast)
{
    const float4* ap = reinterpret_cast<const float4*>(Al + (size_t)d * 16);
    #pragma unroll
    for (int i = 0; i < 4; ++i) {
        float4 v = ap[i];
        a[4*i+0] = -expf(v.x); a[4*i+1] = -expf(v.y);
        a[4*i+2] = -expf(v.z); a[4*i+3] = -expf(v.w);
    }
    fast = true;
    #pragma unroll
    for (int n = 1; n < 16; ++n)
        fast = fast && (fabsf(a[n] - (float)(n + 1) * a[0]) <= 1e-4f * (float)(n + 1));
}

#define LD16(dst, src_t)                                              \
    {                                                                 \
        const float4* q_ = reinterpret_cast<const float4*>(src_t);    \
        float4 q0 = q_[0], q1 = q_[1], q2 = q_[2], q3 = q_[3];        \
        dst[0]=q0.x; dst[1]=q0.y; dst[2]=q0.z; dst[3]=q0.w;           \
        dst[4]=q1.x; dst[5]=q1.y; dst[6]=q1.z; dst[7]=q1.w;           \
        dst[8]=q2.x; dst[9]=q2.y; dst[10]=q2.z; dst[11]=q2.w;         \
        dst[12]=q3.x; dst[13]=q3.y; dst[14]=q3.z; dst[15]=q3.w;       \
    }

__global__ __launch_bounds__(256)
void scan_pass1(const ushort* __restrict__ xi_f, const ushort* __restrict__ xi_b,
                const float* __restrict__ dt_f, const float* __restrict__ dt_b,
                const float* __restrict__ xd_f, const float* __restrict__ xd_b,
                const float* __restrict__ Al_f, const float* __restrict__ Al_b,
                float* __restrict__ Acum, float* __restrict__ Hloc)
{
    __shared__ float Bsh[CLEN][16];
    int db, b, dir, chunk, d; size_t row0;
    scan_head(blockIdx.x, threadIdx.x, db, b, dir, chunk, d, row0);

    const ushort* xi = dir ? xi_b : xi_f;
    const float* dt  = dir ? dt_b : dt_f;
    const float* xd  = dir ? xd_b : xd_f;
    const float* Al  = dir ? Al_b : Al_f;

    float a[16]; bool fast;
    load_a16(Al, d, a, fast);

    for (int i = threadIdx.x; i < CLEN * 16; i += 256) {
        int r = i >> 4, n = i & 15;
        Bsh[r][n] = xd[(row0 + r) * 32 + n];
    }
    __syncthreads();

    const ushort* xip = xi + row0 * 512 + d;
    const float*  dtp = dt + row0 * 512 + d;
    float h[16] = {};
    float sumdt = 0.f;

    if (fast) {
        #pragma unroll 2
        for (int t = 0; t < CLEN; ++t) {
            float bn[16]; LD16(bn, Bsh[t]);
            float dtv = dtp[(size_t)t * 512];
            float xiv = b2f(xip[(size_t)t * 512]);
            float dbx = dtv * xiv;
            sumdt += dtv;
            float q = __expf(dtv * a[0]);
            float dA = q;
            #pragma unroll
            for (int n = 0; n < 16; ++n) {
                h[n] = fmaf(dA, h[n], dbx * bn[n]);
                dA *= q;
            }
        }
    } else {
        #pragma unroll 2
        for (int t = 0; t < CLEN; ++t) {
            float bn[16]; LD16(bn, Bsh[t]);
            float dtv = dtp[(size_t)t * 512];
            float xiv = b2f(xip[(size_t)t * 512]);
            float dbx = dtv * xiv;
            sumdt += dtv;
            #pragma unroll
            for (int n = 0; n < 16; ++n) {
                float dA = __expf(dtv * a[n]);
                h[n] = fmaf(dA, h[n], dbx * bn[n]);
            }
        }
    }

    size_t si = ((size_t)((db * NCHUNK + chunk) * 512 + d)) * 16;
    float4* Ao = reinterpret_cast<float4*>(Acum + si);
    float4* Ho = reinterpret_cast<float4*>(Hloc + si);
    #pragma unroll
    for (int i = 0; i < 4; ++i) {
        Ao[i] = make_float4(__expf(a[4*i+0]*sumdt), __expf(a[4*i+1]*sumdt),
                            __expf(a[4*i+2]*sumdt), __expf(a[4*i+3]*sumdt));
        Ho[i] = make_float4(h[4*i+0], h[4*i+1], h[4*i+2], h[4*i+3]);
    }
}

__global__ __launch_bounds__(256)
void scan_pass2(const float* __restrict__ Acum, const float* __restrict__ Hloc,
                float* __restrict__ Hin)
{
    int tid = blockIdx.x * 256 + threadIdx.x;
    int db = tid >> 13;
    int dn = tid & 8191;
    size_t base = (size_t)db * NCHUNK * 8192 + dn;
    float h = 0.f;
    #pragma unroll 8
    for (int c = 0; c < NCHUNK; ++c) {
        size_t si = base + (size_t)c * 8192;
        Hin[si] = h;
        h = fmaf(Acum[si], h, Hloc[si]);
    }
}

__global__ __launch_bounds__(256)
void scan_pass3(const ushort* __restrict__ xi_f, const ushort* __restrict__ xi_b,
                const float* __restrict__ dt_f, const float* __restrict__ dt_b,
                const float* __restrict__ xd_f, const float* __restrict__ xd_b,
                const float* __restrict__ Al_f, const float* __restrict__ Al_b,
                const ushort* __restrict__ xz_f, const ushort* __restrict__ xz_b,
                const float* __restrict__ D_f, const float* __restrict__ D_b,
                const float* __restrict__ Hin,
                ushort* __restrict__ y_f, ushort* __restrict__ y_b)
{
    __shared__ float Bsh[CLEN][16];
    __shared__ float Csh[CLEN][16];
    int db, b, dir, chunk, d; size_t row0;
    scan_head(blockIdx.x, threadIdx.x, db, b, dir, chunk, d, row0);

    const ushort* xi = dir ? xi_b : xi_f;
    const float* dt  = dir ? dt_b : dt_f;
    const float* xd  = dir ? xd_b : xd_f;
    const float* Al  = dir ? Al_b : Al_f;
    const ushort* xz = dir ? xz_b : xz_f;
    const float* Dv  = dir ? D_b  : D_f;
    ushort*      y   = dir ? y_b  : y_f;

    float a[16]; bool fast;
    load_a16(Al, d, a, fast);
    float Dd = Dv[d];

    for (int i = threadIdx.x; i < CLEN * 32; i += 256) {
        int r = i >> 5, c = i & 31;
        float v = xd[(row0 + r) * 32 + c];
        if (c < 16) Bsh[r][c] = v; else Csh[r][c - 16] = v;
    }
    __syncthreads();

    float h[16];
    {
        size_t si = ((size_t)((db * NCHUNK + chunk) * 512 + d)) * 16;
        const float4* hp = reinterpret_cast<const float4*>(Hin + si);
        #pragma unroll
        for (int i = 0; i < 4; ++i) {
            float4 v = hp[i];
            h[4*i+0] = v.x; h[4*i+1] = v.y; h[4*i+2] = v.z; h[4*i+3] = v.w;
        }
    }

    const ushort* xip = xi + row0 * 512 + d;
    const float*  dtp = dt + row0 * 512 + d;
    const ushort* zp  = xz + row0 * 1024 + 512 + d;
    ushort*       yp  = y  + row0 * 512 + d;

    if (fast) {
        #pragma unroll 2
        for (int t = 0; t < CLEN; ++t) {
            float bn[16]; LD16(bn, Bsh[t]);
            float cn[16]; LD16(cn, Csh[t]);
            float dtv = dtp[(size_t)t * 512];
            float xiv = b2f(xip[(size_t)t * 512]);
            float zv  = b2f(zp[(size_t)t * 1024]);
            float dbx = dtv * xiv;
            float q = __expf(dtv * a[0]);
            float dA = q;
            float yacc = 0.f;
            #pragma unroll
            for (int n = 0; n < 16; ++n) {
                h[n] = fmaf(dA, h[n], dbx * bn[n]);
                yacc = fmaf(h[n], cn[n], yacc);
                dA *= q;
            }
            yp[(size_t)t * 512] = f2b(fmaf(xiv, Dd, yacc) * siluf(zv));
        }
    } else {
        #pragma unroll 2
        for (int t = 0; t < CLEN; ++t) {
            float bn[16]; LD16(bn, Bsh[t]);
            float cn[16]; LD16(cn, Csh[t]);
            float dtv = dtp[(size_t)t * 512];
            float xiv = b2f(xip[(size_t)t * 512]);
            float zv  = b2f(zp[(size_t)t * 1024]);
            float dbx = dtv * xiv;
            float yacc = 0.f;
            #pragma unroll
            for (int n = 0; n < 16; ++n) {
                float dA = __expf(dtv * a[n]);
                h[n] = fmaf(dA, h[n], dbx * bn[n]);
                yacc = fmaf(h[n], cn[n], yacc);
            }
            yp[(size_t)t * 512] = f2b(fmaf(xiv, Dd, yacc) * siluf(zv));
        }
    }
}

// ---------------------------------------------------------------------------
extern "C" void kernel_launch(void* const* d_in, const int* in_sizes, int n_in,
                              void* d_out, int out_size, void* d_ws, size_t ws_size,
                              hipStream_t stream)
{
    const float* x       = (const float*)d_in[0];
    const float* fW_in   = (const float*)d_in[1];
    const float* fconv_w = (const float*)d_in[2];
    const float* fconv_b = (const float*)d_in[3];
    const float* fW_x    = (const float*)d_in[4];
    const float* fW_dt   = (const float*)d_in[5];
    const float* fb_dt   = (const float*)d_in[6];
    const float* fA_log  = (const float*)d_in[7];
    const float* fD      = (const float*)d_in[8];
    const float* fW_out  = (const float*)d_in[9];
    const float* bW_in   = (const float*)d_in[10];
    const float* bconv_w = (const float*)d_in[11];
    const float* bconv_b = (const float*)d_in[12];
    const float* bW_x    = (const float*)d_in[13];
    const float* bW_dt   = (const float*)d_in[14];
    const float* bb_dt   = (const float*)d_in[15];
    const float* bA_log  = (const float*)d_in[16];
    const float* bD      = (const float*)d_in[17];
    const float* bW_out  = (const float*)d_in[18];
    const float* merge   = (const float*)d_in[19];
    float* out = (float*)d_out;

    char* ws = (char*)d_ws;
    ushort* xbh     = (ushort*)ws; ws += (size_t)ROWS * 256 * 2;
    ushort* WinT_f  = (ushort*)ws; ws += (size_t)1024 * 256 * 2;
    ushort* WinT_b  = (ushort*)ws; ws += (size_t)1024 * 256 * 2;
    ushort* WfT     = (ushort*)ws; ws += (size_t)256 * 512 * 2;
    ushort* WbT     = (ushort*)ws; ws += (size_t)256 * 512 * 2;
    ushort* WcT_f   = (ushort*)ws; ws += (size_t)512 * 512 * 2;
    ushort* WcT_b   = (ushort*)ws; ws += (size_t)512 * 512 * 2;
    ushort* xz_f    = (ushort*)ws; ws += (size_t)ROWS * 1024 * 2;
    ushort* xz_b    = (ushort*)ws; ws += (size_t)ROWS * 1024 * 2;
    ushort* xi_f    = (ushort*)ws; ws += (size_t)ROWS * 512 * 2;
    ushort* xi_b    = (ushort*)ws; ws += (size_t)ROWS * 512 * 2;
    ushort* y_f     = (ushort*)ws; ws += (size_t)ROWS * 512 * 2;
    ushort* y_b     = (ushort*)ws; ws += (size_t)ROWS * 512 * 2;
    float*  dt_f    = (float*)ws;  ws += (size_t)ROWS * 512 * 4;
    float*  dt_b    = (float*)ws;  ws += (size_t)ROWS * 512 * 4;
    float*  xd_f    = (float*)ws;  ws += (size_t)ROWS * 32 * 4;
    float*  xd_b    = (float*)ws;  ws += (size_t)ROWS * 32 * 4;
    float*  Acum    = (float*)ws;  ws += (size_t)4 * NCHUNK * 8192 * 4;
    float*  Hloc    = (float*)ws;  ws += (size_t)4 * NCHUNK * 8192 * 4;
    float*  Hin     = (float*)ws;  ws += (size_t)4 * NCHUNK * 8192 * 4;

    dim3 blk(256);

    // prep
    cvt_bf16<<<1024, blk, 0, stream>>>(x, xbh);
    transpose_w<<<128, blk, 0, stream>>>(fW_in, WinT_f, 256, 1024);
    transpose_w<<<128, blk, 0, stream>>>(bW_in, WinT_b, 256, 1024);
    fusewT<<<512, blk, 0, stream>>>(fW_out, merge, WfT, 0);
    fusewT<<<512, blk, 0, stream>>>(bW_out, merge, WbT, 256);
    wcompT<<<128, blk, 0, stream>>>(fW_x, fW_dt, WcT_f);
    wcompT<<<128, blk, 0, stream>>>(bW_x, bW_dt, WcT_b);

    // G1: xz = x @ W_in, both dirs
    mfma_gemm<128, 128, 1><<<dim3(8, 64, 2), blk, 0, stream>>>(
        xbh, xbh, WinT_f, WinT_b, xz_f, xz_b, nullptr, nullptr,
        256, 1024, 0, 1, 1, 1);

    // conv + silu (both dirs)
    conv_kernel<<<4096, blk, 0, stream>>>(xz_f, xz_b, fconv_w, bconv_w,
                                          fconv_b, bconv_b, xi_f, xi_b);

    // dt = softplus(xi @ Wcomp + b_dt)  (MFMA, fp32 out)
    mfma_gemm<128, 128, 2><<<dim3(4, 64, 2), blk, 0, stream>>>(
        xi_f, xi_b, WcT_f, WcT_b, dt_f, dt_b, fb_dt, bb_dt,
        512, 512, 0, 0, 1, 1);

    // xd = xi @ W_x[:, 16:48]  (B,C only; N=32)
    gemm64m<<<dim3(1, 128, 2), blk, 0, stream>>>(xi_f, xi_b, fW_x + 16, bW_x + 16,
                                                 xd_f, xd_b, 32, 512, 512, 48, 32);

    // chunked scan
    scan_pass1<<<1024, blk, 0, stream>>>(xi_f, xi_b, dt_f, dt_b, xd_f, xd_b,
                                         fA_log, bA_log, Acum, Hloc);
    scan_pass2<<<128, blk, 0, stream>>>(Acum, Hloc, Hin);
    scan_pass3<<<1024, blk, 0, stream>>>(xi_f, xi_b, dt_f, dt_b, xd_f, xd_b,
                                         fA_log, bA_log, xz_f, xz_b, fD, bD,
                                         Hin, y_f, y_b);

    // G5: out = y_f @ WfT^T + flip(y_b) @ WbT^T
    mfma_gemm<64, 64, 0><<<dim3(4, 128, 1), blk, 0, stream>>>(
        y_f, y_b, WfT, WbT, out, out, nullptr, nullptr,
        512, 256, 0, 1, 0, 2);
}

// Round 6
// 226.021 us; speedup vs baseline: 9.4366x; 1.1022x over previous
//
#include <hip/hip_runtime.h>
#include <math.h>

#define T_SEQ 4096
#define ROWS 8192
#define NCHUNK 128
#define CLEN 32

typedef __attribute__((ext_vector_type(4))) float f32x4;
typedef __attribute__((ext_vector_type(8))) short s16x8;

__device__ __forceinline__ float siluf(float x) { return x / (1.f + __expf(-x)); }
__device__ __forceinline__ float softplusf(float x) {
    return fmaxf(x, 0.f) + log1pf(__expf(-fabsf(x)));
}
__device__ __forceinline__ ushort f2b(float f) {
    uint u = __float_as_uint(f);
    u += 0x7fffu + ((u >> 16) & 1u);
    return (ushort)(u >> 16);
}
__device__ __forceinline__ float b2f(ushort h) { return __uint_as_float(((uint)h) << 16); }

// direct global->LDS, 16B per lane.  LDS dest is wave-uniform base + lane*16;
// global src is per-lane.
__device__ __forceinline__ void gl16(const ushort* g, const char* l)
{
    __builtin_amdgcn_global_load_lds(
        (const __attribute__((address_space(1))) void*)g,
        (__attribute__((address_space(3))) void*)l,
        16, 0, 0);
}

// ---------------------------------------------------------------------------
// fp32 -> bf16 bulk convert (8 elems/thread)
// ---------------------------------------------------------------------------
__global__ __launch_bounds__(256)
void cvt_bf16(const float* __restrict__ in, ushort* __restrict__ out)
{
    int i = blockIdx.x * 256 + threadIdx.x;
    const float4* p = reinterpret_cast<const float4*>(in) + (size_t)i * 2;
    float4 a = p[0], b = p[1];
    s16x8 v;
    v[0] = (short)f2b(a.x); v[1] = (short)f2b(a.y); v[2] = (short)f2b(a.z); v[3] = (short)f2b(a.w);
    v[4] = (short)f2b(b.x); v[5] = (short)f2b(b.y); v[6] = (short)f2b(b.z); v[7] = (short)f2b(b.w);
    *reinterpret_cast<s16x8*>(out + (size_t)i * 8) = v;
}

// ---------------------------------------------------------------------------
// W [Kdim][Ndim] fp32 -> WT [Ndim][Kdim] bf16
// ---------------------------------------------------------------------------
__global__ __launch_bounds__(256)
void transpose_w(const float* __restrict__ W, ushort* __restrict__ WT, int Kdim, int Ndim)
{
    int idx = blockIdx.x * 256 + threadIdx.x;
    int kg8 = Kdim >> 3;
    if (idx >= Ndim * kg8) return;
    int n = idx / kg8, kg = idx - n * kg8;
    s16x8 v;
    #pragma unroll
    for (int i = 0; i < 8; ++i)
        v[i] = (short)f2b(W[(size_t)(kg * 8 + i) * Ndim + n]);
    *reinterpret_cast<s16x8*>(WT + (size_t)n * Kdim + kg * 8) = v;
}

// ---------------------------------------------------------------------------
// Fused+transposed output weights: WT[j][d] = sum_m W_out[d][m]*merge[mrow0+m][j]
// ---------------------------------------------------------------------------
__global__ __launch_bounds__(256)
void fusewT(const float* __restrict__ W_out, const float* __restrict__ merge,
            ushort* __restrict__ WT, int mrow0)
{
    int idx = blockIdx.x * 256 + threadIdx.x;   // d*256 + j
    int dd = idx >> 8, j = idx & 255;
    float acc = 0.f;
    const float* wr = W_out + dd * 256;
    const float* mc = merge + (size_t)mrow0 * 256 + j;
    #pragma unroll 4
    for (int m = 0; m < 256; ++m)
        acc = fmaf(wr[m], mc[(size_t)m * 256], acc);
    WT[(size_t)j * 512 + dd] = f2b(acc);
}

// ---------------------------------------------------------------------------
// Wall [576][512] bf16:
//   rows 0..511:   (W_x[:, :16] @ W_dt)^T   (composed dt weight)
//   rows 512..543: W_x[:, 16+(n-512)]^T     (B,C columns)
//   rows 544..575: 0
// ---------------------------------------------------------------------------
__global__ __launch_bounds__(256)
void wallT(const float* __restrict__ Wx, const float* __restrict__ Wdt,
           ushort* __restrict__ WT)
{
    int idx = blockIdx.x * 256 + threadIdx.x;   // n*64 + kg
    int n = idx >> 6, kg = idx & 63;
    s16x8 v;
    #pragma unroll
    for (int i = 0; i < 8; ++i) {
        int k = kg * 8 + i;
        float acc = 0.f;
        if (n < 512) {
            #pragma unroll
            for (int j = 0; j < 16; ++j)
                acc = fmaf(Wx[k * 48 + j], Wdt[j * 512 + n], acc);
        } else if (n < 544) {
            acc = Wx[k * 48 + 16 + (n - 512)];
        }
        v[i] = (short)f2b(acc);
    }
    *reinterpret_cast<s16x8*>(WT + (size_t)n * 512 + kg * 8) = v;
}

// ---------------------------------------------------------------------------
// bf16 MFMA GEMM, m97 structure: global_load_lds staging, single-buffer
// 2-barrier K-loop, XOR-swizzled LDS (linear dest + inv-swz source + swz read).
// C = sum_seg A_seg(bf16 MxK, opt row-flip) @ BT_seg([N][K])^T
// 4 waves 2x2, wave tile (BM/2)x(BN/2), 16x16x32 frags, BK=64.
// EPI: 0 = f32 store, 1 = bf16 store,
//      2 = col<512: dt=softplus(acc+bias[c]); col 512..543: xd; else skip.
// ---------------------------------------------------------------------------
template<int BM, int BN, int EPI>
__global__ __launch_bounds__(256)
void mgemm(const ushort* __restrict__ A0, const ushort* __restrict__ A1,
           const ushort* __restrict__ B0, const ushort* __restrict__ B1,
           void* __restrict__ C0, void* __restrict__ C1,
           const float* __restrict__ bias0, const float* __restrict__ bias1,
           float* __restrict__ X0, float* __restrict__ X1,
           int K, int ldc, int flip0, int flip1, int zmode, int nseg)
{
    constexpr int MF = BM / 32, NF = BN / 32;
    constexpr int ABYTES = BM * 128;
    __shared__ char lds[BM * 128 + BN * 128];

    const int tid = threadIdx.x;
    const int L = tid & 63, w = tid >> 6;
    const int wm = w >> 1, wn = w & 1;
    const int m0 = blockIdx.y * BM, n0 = blockIdx.x * BN;

    f32x4 acc[MF][NF];
    #pragma unroll
    for (int i = 0; i < MF; ++i)
        #pragma unroll
        for (int j = 0; j < NF; ++j)
            acc[i][j] = (f32x4){0.f, 0.f, 0.f, 0.f};

    const int rsub = L >> 3;               // row within 8-row stripe
    const int q = (L & 7) ^ rsub;          // inverse-swizzled source slot
    const int sb = zmode ? blockIdx.z : 0;
    const int se = zmode ? sb + 1 : nseg;

    for (int s = sb; s < se; ++s) {
        const ushort* Ap = s ? A1 : A0;
        const ushort* Bp = s ? B1 : B0;
        const int flip = s ? flip1 : flip0;
        for (int k0 = 0; k0 < K; k0 += 64) {
            #pragma unroll
            for (int c = 0; c < BM / 32; ++c) {
                int stripe = w * (BM / 32) + c;
                int rg = m0 + stripe * 8 + rsub;
                if (flip) rg ^= (T_SEQ - 1);
                gl16(Ap + (size_t)rg * K + k0 + q * 8, lds + stripe * 1024);
            }
            #pragma unroll
            for (int c = 0; c < BN / 32; ++c) {
                int stripe = w * (BN / 32) + c;
                int ng = n0 + stripe * 8 + rsub;
                gl16(Bp + (size_t)ng * K + k0 + q * 8, lds + ABYTES + stripe * 1024);
            }
            __syncthreads();   // vmcnt(0) drained by compiler before barrier
            #pragma unroll
            for (int kk = 0; kk < 2; ++kk) {
                const int sw = (((kk * 4 + (L >> 4)) ^ (L & 7)) << 4);
                s16x8 af[MF], bf[NF];
                #pragma unroll
                for (int i = 0; i < MF; ++i) {
                    int R = wm * (BM / 2) + i * 16 + (L & 15);
                    af[i] = *reinterpret_cast<const s16x8*>(lds + R * 128 + sw);
                }
                #pragma unroll
                for (int j = 0; j < NF; ++j) {
                    int R = wn * (BN / 2) + j * 16 + (L & 15);
                    bf[j] = *reinterpret_cast<const s16x8*>(lds + ABYTES + R * 128 + sw);
                }
                #pragma unroll
                for (int i = 0; i < MF; ++i)
                    #pragma unroll
                    for (int j = 0; j < NF; ++j)
                        acc[i][j] = __builtin_amdgcn_mfma_f32_16x16x32_bf16(
                            af[i], bf[j], acc[i][j], 0, 0, 0);
            }
            __syncthreads();
        }
    }

    void* Cv = (zmode && blockIdx.z) ? C1 : C0;
    const float* bias = (zmode && blockIdx.z) ? bias1 : bias0;
    float* Xv = (zmode && blockIdx.z) ? X1 : X0;
    #pragma unroll
    for (int i = 0; i < MF; ++i) {
        #pragma unroll
        for (int j = 0; j < NF; ++j) {
            int r0 = m0 + wm * (BM / 2) + i * 16 + ((L >> 4) << 2);
            int c  = n0 + wn * (BN / 2) + j * 16 + (L & 15);
            if (EPI == 2) {
                if (c < 512) {
                    float bv = bias[c];
                    #pragma unroll
                    for (int r = 0; r < 4; ++r)
                        ((float*)Cv)[(size_t)(r0 + r) * 512 + c] =
                            softplusf(acc[i][j][r] + bv);
                } else if (c < 544) {
                    #pragma unroll
                    for (int r = 0; r < 4; ++r)
                        Xv[(size_t)(r0 + r) * 32 + (c - 512)] = acc[i][j][r];
                }
            } else {
                #pragma unroll
                for (int r = 0; r < 4; ++r) {
                    size_t o = (size_t)(r0 + r) * ldc + c;
                    if (EPI == 1) ((ushort*)Cv)[o] = f2b(acc[i][j][r]);
                    else          ((float*)Cv)[o]  = acc[i][j][r];
                }
            }
        }
    }
}

// ---------------------------------------------------------------------------
// Causal depthwise conv (4 taps) + bias + silu, bf16 in/out, 8 rows/thread.
// ---------------------------------------------------------------------------
__global__ __launch_bounds__(256)
void conv_kernel(const ushort* __restrict__ xz_f, const ushort* __restrict__ xz_b,
                 const float* __restrict__ w_f, const float* __restrict__ w_b,
                 const float* __restrict__ bias_f, const float* __restrict__ bias_b,
                 ushort* __restrict__ xi_f, ushort* __restrict__ xi_b)
{
    int gid = blockIdx.x;
    int dir = gid >> 11;
    const ushort* xz  = dir ? xz_b : xz_f;
    const float*  w   = dir ? w_b : w_f;
    const float*  bia = dir ? bias_b : bias_f;
    ushort*       xi  = dir ? xi_b : xi_f;

    int idx = (gid & 2047) * 256 + threadIdx.x;   // rb*512 + d
    int rb = idx >> 9, d = idx & 511;
    int r0 = rb * 8;
    int t0 = r0 & (T_SEQ - 1);
    float w0 = w[d * 4 + 0], w1 = w[d * 4 + 1], w2 = w[d * 4 + 2], w3 = w[d * 4 + 3];
    float bs = bia[d];

    float xv[11];
    #pragma unroll
    for (int k = 0; k < 11; ++k) {
        int tt = t0 - 3 + k;
        xv[k] = (tt >= 0) ? b2f(xz[(size_t)(r0 - 3 + k) * 1024 + d]) : 0.f;
    }
    #pragma unroll
    for (int j = 0; j < 8; ++j) {
        float acc = bs;
        acc = fmaf(w0, xv[j + 0], acc);
        acc = fmaf(w1, xv[j + 1], acc);
        acc = fmaf(w2, xv[j + 2], acc);
        acc = fmaf(w3, xv[j + 3], acc);
        xi[(size_t)(r0 + j) * 512 + d] = f2b(siluf(acc));
    }
}

// ---------------------------------------------------------------------------
// Chunked scan.  Thread owns channel d (16 states in regs); dt precomputed.
// bid = ((db*NCHUNK + chunk)*2 + half); d = half*256 + tid.
// Fast path: a[n] == (n+1)*a[0]  =>  dA_n = q^(n+1), q = exp(dt*a0).
// ---------------------------------------------------------------------------
__device__ __forceinline__ void scan_head(int bid, int tid,
    int& db, int& b, int& dir, int& chunk, int& d, size_t& row0)
{
    int half = bid & 1;
    int tmp = bid >> 1;
    chunk = tmp & (NCHUNK - 1);
    db = tmp >> 7;
    b = db & 1; dir = db >> 1;
    d = half * 256 + tid;
    row0 = (size_t)b * T_SEQ + (size_t)chunk * CLEN;
}

__device__ __forceinline__ void load_a16(const float* __restrict__ Al, int d,
                                         float* a, bool& fast)
{
    const float4* ap = reinterpret_cast<const float4*>(Al + (size_t)d * 16);
    #pragma unroll
    for (int i = 0; i < 4; ++i) {
        float4 v = ap[i];
        a[4*i+0] = -expf(v.x); a[4*i+1] = -expf(v.y);
        a[4*i+2] = -expf(v.z); a[4*i+3] = -expf(v.w);
    }
    fast = true;
    #pragma unroll
    for (int n = 1; n < 16; ++n)
        fast = fast && (fabsf(a[n] - (float)(n + 1) * a[0]) <= 1e-4f * (float)(n + 1));
}

#define LD16(dst, src_t)                                              \
    {                                                                 \
        const float4* q_ = reinterpret_cast<const float4*>(src_t);    \
        float4 q0 = q_[0], q1 = q_[1], q2 = q_[2], q3 = q_[3];        \
        dst[0]=q0.x; dst[1]=q0.y; dst[2]=q0.z; dst[3]=q0.w;           \
        dst[4]=q1.x; dst[5]=q1.y; dst[6]=q1.z; dst[7]=q1.w;           \
        dst[8]=q2.x; dst[9]=q2.y; dst[10]=q2.z; dst[11]=q2.w;         \
        dst[12]=q3.x; dst[13]=q3.y; dst[14]=q3.z; dst[15]=q3.w;       \
    }

__global__ __launch_bounds__(256)
void scan_pass1(const ushort* __restrict__ xi_f, const ushort* __restrict__ xi_b,
                const float* __restrict__ dt_f, const float* __restrict__ dt_b,
                const float* __restrict__ xd_f, const float* __restrict__ xd_b,
                const float* __restrict__ Al_f, const float* __restrict__ Al_b,
                float* __restrict__ Acum, float* __restrict__ Hloc)
{
    __shared__ float Bsh[CLEN][16];
    int db, b, dir, chunk, d; size_t row0;
    scan_head(blockIdx.x, threadIdx.x, db, b, dir, chunk, d, row0);

    const ushort* xi = dir ? xi_b : xi_f;
    const float* dt  = dir ? dt_b : dt_f;
    const float* xd  = dir ? xd_b : xd_f;
    const float* Al  = dir ? Al_b : Al_f;

    float a[16]; bool fast;
    load_a16(Al, d, a, fast);

    for (int i = threadIdx.x; i < CLEN * 16; i += 256) {
        int r = i >> 4, n = i & 15;
        Bsh[r][n] = xd[(row0 + r) * 32 + n];
    }
    __syncthreads();

    const ushort* xip = xi + row0 * 512 + d;
    const float*  dtp = dt + row0 * 512 + d;
    float h[16] = {};
    float sumdt = 0.f;

    if (fast) {
        #pragma unroll 2
        for (int t = 0; t < CLEN; ++t) {
            float bn[16]; LD16(bn, Bsh[t]);
            float dtv = dtp[(size_t)t * 512];
            float xiv = b2f(xip[(size_t)t * 512]);
            float dbx = dtv * xiv;
            sumdt += dtv;
            float qv = __expf(dtv * a[0]);
            float dA = qv;
            #pragma unroll
            for (int n = 0; n < 16; ++n) {
                h[n] = fmaf(dA, h[n], dbx * bn[n]);
                dA *= qv;
            }
        }
    } else {
        #pragma unroll 2
        for (int t = 0; t < CLEN; ++t) {
            float bn[16]; LD16(bn, Bsh[t]);
            float dtv = dtp[(size_t)t * 512];
            float xiv = b2f(xip[(size_t)t * 512]);
            float dbx = dtv * xiv;
            sumdt += dtv;
            #pragma unroll
            for (int n = 0; n < 16; ++n) {
                float dA = __expf(dtv * a[n]);
                h[n] = fmaf(dA, h[n], dbx * bn[n]);
            }
        }
    }

    size_t si = ((size_t)((db * NCHUNK + chunk) * 512 + d)) * 16;
    float4* Ao = reinterpret_cast<float4*>(Acum + si);
    float4* Ho = reinterpret_cast<float4*>(Hloc + si);
    #pragma unroll
    for (int i = 0; i < 4; ++i) {
        Ao[i] = make_float4(__expf(a[4*i+0]*sumdt), __expf(a[4*i+1]*sumdt),
                            __expf(a[4*i+2]*sumdt), __expf(a[4*i+3]*sumdt));
        Ho[i] = make_float4(h[4*i+0], h[4*i+1], h[4*i+2], h[4*i+3]);
    }
}

__global__ __launch_bounds__(256)
void scan_pass2(const float* __restrict__ Acum, const float* __restrict__ Hloc,
                float* __restrict__ Hin)
{
    int tid = blockIdx.x * 256 + threadIdx.x;
    int db = tid >> 13;
    int dn = tid & 8191;
    size_t base = (size_t)db * NCHUNK * 8192 + dn;
    float h = 0.f;
    #pragma unroll 8
    for (int c = 0; c < NCHUNK; ++c) {
        size_t si = base + (size_t)c * 8192;
        Hin[si] = h;
        h = fmaf(Acum[si], h, Hloc[si]);
    }
}

__global__ __launch_bounds__(256)
void scan_pass3(const ushort* __restrict__ xi_f, const ushort* __restrict__ xi_b,
                const float* __restrict__ dt_f, const float* __restrict__ dt_b,
                const float* __restrict__ xd_f, const float* __restrict__ xd_b,
                const float* __restrict__ Al_f, const float* __restrict__ Al_b,
                const ushort* __restrict__ xz_f, const ushort* __restrict__ xz_b,
                const float* __restrict__ D_f, const float* __restrict__ D_b,
                const float* __restrict__ Hin,
                ushort* __restrict__ y_f, ushort* __restrict__ y_b)
{
    __shared__ float Bsh[CLEN][16];
    __shared__ float Csh[CLEN][16];
    int db, b, dir, chunk, d; size_t row0;
    scan_head(blockIdx.x, threadIdx.x, db, b, dir, chunk, d, row0);

    const ushort* xi = dir ? xi_b : xi_f;
    const float* dt  = dir ? dt_b : dt_f;
    const float* xd  = dir ? xd_b : xd_f;
    const float* Al  = dir ? Al_b : Al_f;
    const ushort* xz = dir ? xz_b : xz_f;
    const float* Dv  = dir ? D_b  : D_f;
    ushort*      y   = dir ? y_b  : y_f;

    float a[16]; bool fast;
    load_a16(Al, d, a, fast);
    float Dd = Dv[d];

    for (int i = threadIdx.x; i < CLEN * 32; i += 256) {
        int r = i >> 5, c = i & 31;
        float v = xd[(row0 + r) * 32 + c];
        if (c < 16) Bsh[r][c] = v; else Csh[r][c - 16] = v;
    }
    __syncthreads();

    float h[16];
    {
        size_t si = ((size_t)((db * NCHUNK + chunk) * 512 + d)) * 16;
        const float4* hp = reinterpret_cast<const float4*>(Hin + si);
        #pragma unroll
        for (int i = 0; i < 4; ++i) {
            float4 v = hp[i];
            h[4*i+0] = v.x; h[4*i+1] = v.y; h[4*i+2] = v.z; h[4*i+3] = v.w;
        }
    }

    const ushort* xip = xi + row0 * 512 + d;
    const float*  dtp = dt + row0 * 512 + d;
    const ushort* zp  = xz + row0 * 1024 + 512 + d;
    ushort*       yp  = y  + row0 * 512 + d;

    if (fast) {
        #pragma unroll 2
        for (int t = 0; t < CLEN; ++t) {
            float bn[16]; LD16(bn, Bsh[t]);
            float cn[16]; LD16(cn, Csh[t]);
            float dtv = dtp[(size_t)t * 512];
            float xiv = b2f(xip[(size_t)t * 512]);
            float zv  = b2f(zp[(size_t)t * 1024]);
            float dbx = dtv * xiv;
            float qv = __expf(dtv * a[0]);
            float dA = qv;
            float yacc = 0.f;
            #pragma unroll
            for (int n = 0; n < 16; ++n) {
                h[n] = fmaf(dA, h[n], dbx * bn[n]);
                yacc = fmaf(h[n], cn[n], yacc);
                dA *= qv;
            }
            yp[(size_t)t * 512] = f2b(fmaf(xiv, Dd, yacc) * siluf(zv));
        }
    } else {
        #pragma unroll 2
        for (int t = 0; t < CLEN; ++t) {
            float bn[16]; LD16(bn, Bsh[t]);
            float cn[16]; LD16(cn, Csh[t]);
            float dtv = dtp[(size_t)t * 512];
            float xiv = b2f(xip[(size_t)t * 512]);
            float zv  = b2f(zp[(size_t)t * 1024]);
            float dbx = dtv * xiv;
            float yacc = 0.f;
            #pragma unroll
            for (int n = 0; n < 16; ++n) {
                float dA = __expf(dtv * a[n]);
                h[n] = fmaf(dA, h[n], dbx * bn[n]);
                yacc = fmaf(h[n], cn[n], yacc);
            }
            yp[(size_t)t * 512] = f2b(fmaf(xiv, Dd, yacc) * siluf(zv));
        }
    }
}

// ---------------------------------------------------------------------------
extern "C" void kernel_launch(void* const* d_in, const int* in_sizes, int n_in,
                              void* d_out, int out_size, void* d_ws, size_t ws_size,
                              hipStream_t stream)
{
    const float* x       = (const float*)d_in[0];
    const float* fW_in   = (const float*)d_in[1];
    const float* fconv_w = (const float*)d_in[2];
    const float* fconv_b = (const float*)d_in[3];
    const float* fW_x    = (const float*)d_in[4];
    const float* fW_dt   = (const float*)d_in[5];
    const float* fb_dt   = (const float*)d_in[6];
    const float* fA_log  = (const float*)d_in[7];
    const float* fD      = (const float*)d_in[8];
    const float* fW_out  = (const float*)d_in[9];
    const float* bW_in   = (const float*)d_in[10];
    const float* bconv_w = (const float*)d_in[11];
    const float* bconv_b = (const float*)d_in[12];
    const float* bW_x    = (const float*)d_in[13];
    const float* bW_dt   = (const float*)d_in[14];
    const float* bb_dt   = (const float*)d_in[15];
    const float* bA_log  = (const float*)d_in[16];
    const float* bD      = (const float*)d_in[17];
    const float* bW_out  = (const float*)d_in[18];
    const float* merge   = (const float*)d_in[19];
    float* out = (float*)d_out;

    char* ws = (char*)d_ws;
    ushort* xbh     = (ushort*)ws; ws += (size_t)ROWS * 256 * 2;
    ushort* WinT_f  = (ushort*)ws; ws += (size_t)1024 * 256 * 2;
    ushort* WinT_b  = (ushort*)ws; ws += (size_t)1024 * 256 * 2;
    ushort* WfT     = (ushort*)ws; ws += (size_t)256 * 512 * 2;
    ushort* WbT     = (ushort*)ws; ws += (size_t)256 * 512 * 2;
    ushort* Wall_f  = (ushort*)ws; ws += (size_t)576 * 512 * 2;
    ushort* Wall_b  = (ushort*)ws; ws += (size_t)576 * 512 * 2;
    ushort* xz_f    = (ushort*)ws; ws += (size_t)ROWS * 1024 * 2;
    ushort* xz_b    = (ushort*)ws; ws += (size_t)ROWS * 1024 * 2;
    ushort* xi_f    = (ushort*)ws; ws += (size_t)ROWS * 512 * 2;
    ushort* xi_b    = (ushort*)ws; ws += (size_t)ROWS * 512 * 2;
    ushort* y_f     = (ushort*)ws; ws += (size_t)ROWS * 512 * 2;
    ushort* y_b     = (ushort*)ws; ws += (size_t)ROWS * 512 * 2;
    float*  dt_f    = (float*)ws;  ws += (size_t)ROWS * 512 * 4;
    float*  dt_b    = (float*)ws;  ws += (size_t)ROWS * 512 * 4;
    float*  xd_f    = (float*)ws;  ws += (size_t)ROWS * 32 * 4;
    float*  xd_b    = (float*)ws;  ws += (size_t)ROWS * 32 * 4;
    float*  Acum    = (float*)ws;  ws += (size_t)4 * NCHUNK * 8192 * 4;
    float*  Hloc    = (float*)ws;  ws += (size_t)4 * NCHUNK * 8192 * 4;
    float*  Hin     = (float*)ws;  ws += (size_t)4 * NCHUNK * 8192 * 4;

    dim3 blk(256);

    // prep
    cvt_bf16<<<1024, blk, 0, stream>>>(x, xbh);
    transpose_w<<<128, blk, 0, stream>>>(fW_in, WinT_f, 256, 1024);
    transpose_w<<<128, blk, 0, stream>>>(bW_in, WinT_b, 256, 1024);
    fusewT<<<512, blk, 0, stream>>>(fW_out, merge, WfT, 0);
    fusewT<<<512, blk, 0, stream>>>(bW_out, merge, WbT, 256);
    wallT<<<144, blk, 0, stream>>>(fW_x, fW_dt, Wall_f);
    wallT<<<144, blk, 0, stream>>>(bW_x, bW_dt, Wall_b);

    // G1: xz = x @ W_in, both dirs (z picks dir; bw flips rows)
    mgemm<128, 128, 1><<<dim3(8, 64, 2), blk, 0, stream>>>(
        xbh, xbh, WinT_f, WinT_b, xz_f, xz_b, nullptr, nullptr, nullptr, nullptr,
        256, 1024, 0, 1, 1, 1);

    // conv + silu (both dirs)
    conv_kernel<<<4096, blk, 0, stream>>>(xz_f, xz_b, fconv_w, bconv_w,
                                          fconv_b, bconv_b, xi_f, xi_b);

    // dt+xd merged: [dt | xd | pad] = xi @ Wall^T ; softplus epilogue on dt
    mgemm<64, 64, 2><<<dim3(9, 128, 2), blk, 0, stream>>>(
        xi_f, xi_b, Wall_f, Wall_b, dt_f, dt_b, fb_dt, bb_dt, xd_f, xd_b,
        512, 512, 0, 0, 1, 1);

    // chunked scan
    scan_pass1<<<1024, blk, 0, stream>>>(xi_f, xi_b, dt_f, dt_b, xd_f, xd_b,
                                         fA_log, bA_log, Acum, Hloc);
    scan_pass2<<<128, blk, 0, stream>>>(Acum, Hloc, Hin);
    scan_pass3<<<1024, blk, 0, stream>>>(xi_f, xi_b, dt_f, dt_b, xd_f, xd_b,
                                         fA_log, bA_log, xz_f, xz_b, fD, bD,
                                         Hin, y_f, y_b);

    // G5: out = y_f @ WfT^T + flip(y_b) @ WbT^T  (seg-accumulated)
    mgemm<64, 64, 0><<<dim3(4, 128, 1), blk, 0, stream>>>(
        y_f, y_b, WfT, WbT, out, out, nullptr, nullptr, nullptr, nullptr,
        512, 256, 0, 1, 0, 2);
}